// Round 13
// baseline (823.755 us; speedup 1.0000x reference)
//
#include <hip/hip_runtime.h>
#include <hip/hip_bf16.h>
#include <math.h>

#define H 64
#define F 18
#define NBKT 128   // buckets for coarse partition

typedef _Float16 f16x8 __attribute__((ext_vector_type(8)));
typedef float f32x4 __attribute__((ext_vector_type(4)));

// ---------------------------------------------------------------- embed ----
__global__ __launch_bounds__(256) void embed_kernel(
    const float* __restrict__ nf, const float* __restrict__ W,
    const float* __restrict__ b, _Float16* __restrict__ xh, int N)
{
    int n = blockIdx.x * 256 + threadIdx.x;
    if (n >= N) return;
    float acc[H];
#pragma unroll
    for (int j = 0; j < H; ++j) acc[j] = b[j];
    const float* f = nf + (long)n * F;
#pragma unroll
    for (int i = 0; i < F; ++i) {
        float c = f[i];
        const float* w = W + i * H;
#pragma unroll
        for (int j = 0; j < H; ++j) acc[j] += c * w[j];
    }
    union { uint4 v[8]; _Float16 h[64]; } O;
#pragma unroll
    for (int j = 0; j < H; ++j) O.h[j] = (_Float16)fmaxf(acc[j], 0.f);
    uint4* xo = (uint4*)(xh + (size_t)n * H);
#pragma unroll
    for (int i = 0; i < 8; ++i) xo[i] = O.v[i];
}

// ------------------------------------------------- B-fragment prepack -----
__global__ __launch_bounds__(256) void packfrag_kernel(
    const float* __restrict__ mW1, const float* __restrict__ aW1,
    f16x8* __restrict__ msgB, f16x8* __restrict__ attB)
{
    int t = blockIdx.x * 256 + threadIdx.x;  // 0..3071
    if (t >= 3072) return;
    int lane = t & 63;
    int frag = t >> 6;            // 0..47
    int l = frag / 24, f = frag % 24;
    int quad = lane >> 4, l15 = lane & 15;
    f16x8 v;
    if (f < 16) {
        int nt = f >> 2, kk = f & 3;
        const float* W = mW1 + (size_t)l * 128 * 64;
#pragma unroll
        for (int j = 0; j < 8; ++j) {
            int k = kk * 32 + quad * 8 + j;
            v[j] = (_Float16)W[k * 64 + nt * 16 + l15];
        }
        msgB[((size_t)l * 16 + f) * 64 + lane] = v;
    } else {
        int f2 = f - 16;
        int nt = f2 >> 2, kk = f2 & 3;
        const float* W = aW1 + (size_t)l * 128 * 32;
#pragma unroll
        for (int j = 0; j < 8; ++j) {
            int k = kk * 32 + quad * 8 + j;
            v[j] = (_Float16)W[k * 32 + nt * 16 + l15];
        }
        attB[((size_t)l * 8 + f2) * 64 + lane] = v;
    }
}

// ---------------------------------------------- update-path precompute ----
__global__ __launch_bounds__(256) void prep_update_kernel(
    const float* __restrict__ mW2, const float* __restrict__ mb2,
    const float* __restrict__ uW1,
    float* __restrict__ M2U, float* __restrict__ mbu)
{
    int t = blockIdx.x * 256 + threadIdx.x;  // 0..8191
    if (t >= 2 * 64 * 64) return;
    int l = t >> 12, r = t & 4095;
    int i = r >> 6, j = r & 63;
    const float* W2 = mW2 + (size_t)l * 4096;
    const float* U1b = uW1 + (size_t)l * 8192 + 4096;  // rows 64..127
    float s = 0.f;
    for (int k = 0; k < 64; ++k) s += W2[i * 64 + k] * U1b[k * 64 + j];
    M2U[t] = s;
    if (i == 0) {
        float sb = 0.f;
        const float* b2 = mb2 + (size_t)l * 64;
        for (int k = 0; k < 64; ++k) sb += b2[k] * U1b[k * 64 + j];
        mbu[l * 64 + j] = sb;
    }
}

// g==1 (M2U) fragment rows are PERMUTED: agg is stored with intra-row
// permutation pos = l15*4 + nt (true column c = nt*16 + l15), so the k-th
// A element multiplies M2U row c(k) = ((k&3)<<4)|(k>>2).
__global__ __launch_bounds__(256) void packfrag_upd_kernel(
    const float* __restrict__ uW1, const float* __restrict__ M2U,
    const float* __restrict__ uW2, f16x8* __restrict__ updB)
{
    int t = blockIdx.x * 256 + threadIdx.x;  // 0..3071
    if (t >= 3072) return;
    int lane = t & 63;
    int frag = t >> 6;  // 0..47
    int l = frag / 24, f = frag % 24;
    int quad = lane >> 4, l15 = lane & 15;
    int g = f >> 3, ff = f & 7;
    int nt = ff >> 1, kk = ff & 1;
    const float* src;
    if (g == 0)      src = uW1 + (size_t)l * 8192;       // rows 0..63
    else if (g == 1) src = M2U + (size_t)l * 4096;
    else             src = uW2 + (size_t)l * 4096;
    f16x8 v;
#pragma unroll
    for (int j = 0; j < 8; ++j) {
        int k = kk * 32 + quad * 8 + j;
        int ks = (g == 1) ? (((k & 3) << 4) | (k >> 2)) : k;
        v[j] = (_Float16)src[ks * 64 + nt * 16 + l15];
    }
    updB[(size_t)frag * 64 + lane] = v;
}

// ----------------------------------------------- counting sort metadata ---
__global__ __launch_bounds__(256) void hist_kernel(
    const int* __restrict__ col, int* __restrict__ deg, int E)
{
    int e = blockIdx.x * 256 + threadIdx.x;
    if (e < E) atomicAdd(deg + col[e], 1);
}

__global__ __launch_bounds__(256) void scan1_kernel(
    const int* __restrict__ deg, int* __restrict__ part,
    int* __restrict__ bsum, int N)
{
    __shared__ int lds[256];
    int t = threadIdx.x;
    int base = blockIdx.x * 1024 + t * 4;
    int v[4];
#pragma unroll
    for (int s = 0; s < 4; ++s) v[s] = (base + s < N) ? deg[base + s] : 0;
    int sum = v[0] + v[1] + v[2] + v[3];
    lds[t] = sum;
    __syncthreads();
    for (int off = 1; off < 256; off <<= 1) {
        int xv = (t >= off) ? lds[t - off] : 0;
        __syncthreads();
        lds[t] += xv;
        __syncthreads();
    }
    int excl = lds[t] - sum;
    if (t == 255) bsum[blockIdx.x] = lds[255];
    int p = excl;
#pragma unroll
    for (int s = 0; s < 4; ++s) {
        if (base + s < N) part[base + s] = p;
        p += v[s];
    }
}

__global__ __launch_bounds__(256) void scan2_kernel(int* __restrict__ bsum, int nb)
{
    __shared__ int lds[256];
    int t = threadIdx.x;
    int v = (t < nb) ? bsum[t] : 0;
    lds[t] = v;
    __syncthreads();
    for (int off = 1; off < 256; off <<= 1) {
        int xv = (t >= off) ? lds[t - off] : 0;
        __syncthreads();
        lds[t] += xv;
        __syncthreads();
    }
    if (t < nb) bsum[t] = lds[t] - v;
}

__global__ __launch_bounds__(256) void scan3_kernel(
    int* __restrict__ part, const int* __restrict__ bsum,
    int* __restrict__ cursor, int N)
{
    int i = blockIdx.x * 256 + threadIdx.x;
    if (i >= N) return;
    int s = part[i] + bsum[i >> 10];
    part[i] = s;
    cursor[i] = s;
}

// ----------------------------------------- coarse bucket partition --------
__global__ __launch_bounds__(256) void count_bucket_kernel(
    const int* __restrict__ col, int* __restrict__ cnt,
    int E, int NB, int BS)
{
    __shared__ int lc[NBKT];
    int t = threadIdx.x;
    if (t < NBKT) lc[t] = 0;
    __syncthreads();
    int base = blockIdx.x * 1024 + t;
#pragma unroll
    for (int s = 0; s < 4; ++s) {
        int e = base + s * 256;
        if (e < E) atomicAdd(lc + (unsigned)col[e] / (unsigned)BS, 1);
    }
    __syncthreads();
    if (t < NBKT) cnt[(size_t)t * NB + blockIdx.x] = lc[t];
}

__global__ __launch_bounds__(256) void place_kernel(
    const int* __restrict__ row, const int* __restrict__ col,
    const float* __restrict__ ew, const int* __restrict__ off,
    int4* __restrict__ edata, int E, int NB, int BS)
{
    __shared__ int lc[NBKT];
    int t = threadIdx.x;
    if (t < NBKT) lc[t] = 0;
    __syncthreads();
    int base = blockIdx.x * 1024 + t;
#pragma unroll
    for (int s = 0; s < 4; ++s) {
        int e = base + s * 256;
        if (e < E) {
            int cv = col[e];
            int c = (unsigned)cv / (unsigned)BS;
            int r = atomicAdd(lc + c, 1);
            int pos = off[(size_t)c * NB + blockIdx.x] + r;
            edata[pos] = make_int4(row[e], cv, __float_as_int(ew[e]), 0);
        }
    }
}

// ----------------------------------------------------------------- edge ----
// Chunk = contiguous bucket range: edges [startp[nlo], startp[nhi]).
// hfw rows stored in PERMUTED layout pos=l15*4+nt -> each lane stores one
// contiguous uint2; a quad's 16 lanes cover the full 128B line in ONE store
// instruction (no write-allocate RMW). fw accumulated straight into fwsum
// via spread atomics (no fwbuf).
__global__ __launch_bounds__(256) void edge_mfma_kernel(
    const _Float16* __restrict__ xh,
    const int4* __restrict__ edata, int* __restrict__ cursor,
    const int* __restrict__ startp,
    const f16x8* __restrict__ msgB,  // [16][64] this layer
    const f16x8* __restrict__ attB,  // [8][64]
    const float* __restrict__ b1, const float* __restrict__ ab1,
    const float* __restrict__ aW2, const float* __restrict__ ab2,
    __hip_bfloat16* __restrict__ hfw, float* __restrict__ fwsum,
    int nlo, int nhi, int N, int E)
{
    int e0 = startp[nlo];
    int e1 = (nhi < N) ? startp[nhi] : E;
    int ecnt = e1 - e0;
    int wid = (blockIdx.x * 256 + threadIdx.x) >> 6;
    int lane = threadIdx.x & 63;
    int wbase = wid * 64;
    if (wbase >= ecnt) return;
    int quad = lane >> 4, l15 = lane & 15;

    f16x8 mb[4][4], ab[2][4];
#pragma unroll
    for (int nt = 0; nt < 4; ++nt)
#pragma unroll
        for (int kk = 0; kk < 4; ++kk)
            mb[nt][kk] = msgB[(nt * 4 + kk) * 64 + lane];
#pragma unroll
    for (int nt = 0; nt < 2; ++nt)
#pragma unroll
        for (int kk = 0; kk < 4; ++kk)
            ab[nt][kk] = attB[(nt * 4 + kk) * 64 + lane];

    float ab1v0 = ab1[l15], ab1v1 = ab1[16 + l15];
    float aw20 = aW2[l15], aw21 = aW2[16 + l15];
    float ab2v = ab2[0];
    float bm[4];
#pragma unroll
    for (int nt = 0; nt < 4; ++nt) bm[nt] = b1[nt * 16 + l15];

    for (int mt = 0; mt < 4; ++mt) {
        int lea = wbase + mt * 16 + l15;     // this lane's A-row edge (local)
        bool av = lea < ecnt;
        int leac = av ? lea : ecnt - 1;
        int4 ed = edata[e0 + leac];
        int rowv = ed.x, colv = ed.y;
        float ewl = __int_as_float(ed.z);
        int p0 = 0;
        if (quad == 0 && av) p0 = atomicAdd(cursor + colv, 1) - e0;
        int pl[4], colc[4];
        float ewc[4];
#pragma unroll
        for (int r = 0; r < 4; ++r) {
            pl[r] = __shfl(p0, quad * 4 + r);
            ewc[r] = __shfl(ewl, quad * 4 + r);
            colc[r] = __shfl(colv, quad * 4 + r);
        }

        const f16x8* rowp = (const f16x8*)(xh + (size_t)rowv * H);
        const f16x8* colp = (const f16x8*)(xh + (size_t)colv * H);
        f16x8 A[4];
        A[0] = rowp[quad];
        A[1] = rowp[4 + quad];
        A[2] = colp[quad];
        A[3] = colp[4 + quad];

        // ---- attention GEMM ----
        f32x4 ac0 = {0.f, 0.f, 0.f, 0.f}, ac1 = {0.f, 0.f, 0.f, 0.f};
#pragma unroll
        for (int kk = 0; kk < 4; ++kk) {
            ac0 = __builtin_amdgcn_mfma_f32_16x16x32_f16(A[kk], ab[0][kk], ac0, 0, 0, 0);
            ac1 = __builtin_amdgcn_mfma_f32_16x16x32_f16(A[kk], ab[1][kk], ac1, 0, 0, 0);
        }
        float p[4];
#pragma unroll
        for (int r = 0; r < 4; ++r) {
            float v0 = fmaxf(ac0[r] + ab1v0, 0.f) * aw20;
            float v1 = fmaxf(ac1[r] + ab1v1, 0.f) * aw21;
            p[r] = v0 + v1;
        }
#pragma unroll
        for (int off = 1; off < 16; off <<= 1) {
#pragma unroll
            for (int r = 0; r < 4; ++r) p[r] += __shfl_xor(p[r], off);
        }
        float fw[4];
#pragma unroll
        for (int r = 0; r < 4; ++r) {
            int leg = wbase + mt * 16 + quad * 4 + r;
            float ewv = (leg < ecnt) ? ewc[r] : 0.f;
            fw[r] = ewv / (1.f + __expf(-(p[r] + ab2v)));
        }

        // ---- message GEMM ----
        f32x4 mc[4];
#pragma unroll
        for (int nt = 0; nt < 4; ++nt) {
            f32x4 cc = {0.f, 0.f, 0.f, 0.f};
#pragma unroll
            for (int kk = 0; kk < 4; ++kk)
                cc = __builtin_amdgcn_mfma_f32_16x16x32_f16(A[kk], mb[nt][kk], cc, 0, 0, 0);
            mc[nt] = cc;
        }

        // ---- epilogue: one uint2 per lane -> full 128B line per row ----
#pragma unroll
        for (int r = 0; r < 4; ++r) {
            int leg = wbase + mt * 16 + quad * 4 + r;
            if (leg < ecnt) {
                union { unsigned short u[4]; uint2 v; } pk;
#pragma unroll
                for (int nt = 0; nt < 4; ++nt) {
                    __hip_bfloat16 hb =
                        __float2bfloat16(fmaxf(mc[nt][r] + bm[nt], 0.f) * fw[r]);
                    pk.u[nt] = *reinterpret_cast<unsigned short*>(&hb);
                }
                *(uint2*)(hfw + (size_t)pl[r] * H + l15 * 4) = pk.v;
            }
        }
        if (l15 == 0) {
#pragma unroll
            for (int r = 0; r < 4; ++r) {
                int leg = wbase + mt * 16 + quad * 4 + r;
                if (leg < ecnt) atomicAdd(fwsum + colc[r], fw[r]);
            }
        }
    }
}

// --------------------------------------------------------------- gather ----
// Chunk node range [nlo,nhi): plain stores (agg f16, permuted layout --
// consumed by the permuted Bm fragment), zero-fill for deg-0, cursor reset.
__global__ __launch_bounds__(256) void gather_kernel(
    const __hip_bfloat16* __restrict__ hfw,
    const int* __restrict__ startp, const int* __restrict__ deg,
    int* __restrict__ cursor, _Float16* __restrict__ agg,
    int nlo, int nhi, int N, int E)
{
    int wid = (blockIdx.x * 256 + threadIdx.x) >> 6;
    int lane = threadIdx.x & 63;
    int n = nlo + wid;
    if (n >= nhi) return;
    int e0 = startp[nlo];
    int s = startp[n];
    int d = deg[n];
    int base = s - e0;
    float acc = 0.f;
    const __hip_bfloat16* hp = hfw + (size_t)base * H + lane;
    for (int i = 0; i < d; ++i) acc += __bfloat162float(hp[(size_t)i * H]);
    agg[(size_t)n * H + lane] = (_Float16)acc;
    if (lane == 0) cursor[n] = s;   // reset for next layer
}

// --------------------------------------------------------------- update ----
__global__ __launch_bounds__(256, 2) void update_mfma_kernel(
    _Float16* __restrict__ xh, const _Float16* __restrict__ agg,
    const float* __restrict__ fwsum,
    const f16x8* __restrict__ Bfrag,  // [24][64] this layer
    const float* __restrict__ mbu,    // [64]
    const float* __restrict__ ub1, const float* __restrict__ ub2, int N)
{
    __shared__ __align__(16) _Float16 hlds[4][16 * 80];
    int wib = threadIdx.x >> 6;
    int lane = threadIdx.x & 63;
    int wid = (blockIdx.x * 256 + threadIdx.x) >> 6;
    int quad = lane >> 4, l15 = lane & 15;
    int nbase = wid * 64;
    if (nbase >= N) return;

    f16x8 Bu[8], Bm[8], Bw[8];
#pragma unroll
    for (int i = 0; i < 8; ++i) {
        Bu[i] = Bfrag[i * 64 + lane];
        Bm[i] = Bfrag[(8 + i) * 64 + lane];
        Bw[i] = Bfrag[(16 + i) * 64 + lane];
    }
    float mbuv[4], b1v[4], b2v[4];
#pragma unroll
    for (int nt = 0; nt < 4; ++nt) {
        mbuv[nt] = mbu[nt * 16 + l15];
        b1v[nt] = ub1[nt * 16 + l15];
        b2v[nt] = ub2[nt * 16 + l15];
    }

    for (int mt = 0; mt < 4; ++mt) {
        int na = nbase + mt * 16 + l15;
        if (na >= N) na = N - 1;
        const f16x8* xrow = (const f16x8*)(xh + (size_t)na * H);
        f16x8 Ax[2];
        Ax[0] = xrow[quad];
        Ax[1] = xrow[4 + quad];
        const f16x8* arow = (const f16x8*)(agg + (size_t)na * H);
        f16x8 Aa[2];
        Aa[0] = arow[quad];
        Aa[1] = arow[4 + quad];

        f32x4 Cx[4], Ca[4];
#pragma unroll
        for (int nt = 0; nt < 4; ++nt) {
            f32x4 cx = {0.f, 0.f, 0.f, 0.f}, ca = {0.f, 0.f, 0.f, 0.f};
#pragma unroll
            for (int kk = 0; kk < 2; ++kk) {
                cx = __builtin_amdgcn_mfma_f32_16x16x32_f16(Ax[kk], Bu[nt * 2 + kk], cx, 0, 0, 0);
                ca = __builtin_amdgcn_mfma_f32_16x16x32_f16(Aa[kk], Bm[nt * 2 + kk], ca, 0, 0, 0);
            }
            Cx[nt] = cx; Ca[nt] = ca;
        }

        int noder = nbase + mt * 16 + quad * 4;
        float fws_r[4], inv_r[4];
#pragma unroll
        for (int r = 0; r < 4; ++r) {
            int ng = noder + r; if (ng >= N) ng = N - 1;
            float fws = fwsum[ng];
            fws_r[r] = fws;
            inv_r[r] = 1.f / fmaxf(fws, 1e-6f);
        }

#pragma unroll
        for (int nt = 0; nt < 4; ++nt) {
#pragma unroll
            for (int r = 0; r < 4; ++r) {
                float hv = fmaxf(Cx[nt][r] + inv_r[r] * Ca[nt][r]
                                 + fws_r[r] * inv_r[r] * mbuv[nt] + b1v[nt], 0.f);
                hlds[wib][(quad * 4 + r) * 80 + nt * 16 + l15] = (_Float16)hv;
            }
        }
        __asm__ __volatile__("s_waitcnt lgkmcnt(0)" ::: "memory");
        f16x8 Ah[2];
        Ah[0] = *(const f16x8*)&hlds[wib][l15 * 80 + quad * 8];
        Ah[1] = *(const f16x8*)&hlds[wib][l15 * 80 + 32 + quad * 8];
        __asm__ __volatile__("s_waitcnt lgkmcnt(0)" ::: "memory");

        f32x4 C2[4];
#pragma unroll
        for (int nt = 0; nt < 4; ++nt) {
            f32x4 cc = {0.f, 0.f, 0.f, 0.f};
#pragma unroll
            for (int kk = 0; kk < 2; ++kk)
                cc = __builtin_amdgcn_mfma_f32_16x16x32_f16(Ah[kk], Bw[nt * 2 + kk], cc, 0, 0, 0);
            C2[nt] = cc;
        }

#pragma unroll
        for (int r = 0; r < 4; ++r) {
            int ng = noder + r;
            if (ng < N) {
#pragma unroll
                for (int nt = 0; nt < 4; ++nt) {
                    size_t idx = (size_t)ng * H + nt * 16 + l15;
                    float xo = (float)xh[idx];
                    xh[idx] = (_Float16)fmaxf(C2[nt][r] + b2v[nt] + xo, 0.f);
                }
            }
        }
    }
}

// ----------------------------------------------------------------- head ----
__global__ __launch_bounds__(256) void max_kernel(
    const _Float16* __restrict__ xh16, unsigned int* __restrict__ serp, int N)
{
    int j = threadIdx.x & (H - 1);
    int g = (blockIdx.x * 256 + threadIdx.x) >> 6;
    int stride = (gridDim.x * 256) >> 6;
    float m = 0.f;  // x >= 0 after relu
    for (int n = g; n < N; n += stride)
        m = fmaxf(m, (float)xh16[(size_t)n * H + j]);
    atomicMax(serp + j, __float_as_uint(m));
}

__global__ void head_kernel(const unsigned int* __restrict__ serp,
                            const float* __restrict__ hW,
                            const float* __restrict__ hb,
                            float* __restrict__ out)
{
    int j = threadIdx.x;  // 64 threads = 1 wave
    float v = __uint_as_float(serp[j]) * hW[j];
#pragma unroll
    for (int off = 32; off > 0; off >>= 1) v += __shfl_down(v, off);
    if (j == 0) out[0] = v + hb[0];
}

// --------------------------------------------------------------- launch ----
extern "C" void kernel_launch(void* const* d_in, const int* in_sizes, int n_in,
                              void* d_out, int out_size, void* d_ws, size_t ws_size,
                              hipStream_t stream)
{
    const float* nf  = (const float*)d_in[0];
    const int*   ei  = (const int*)d_in[1];
    const float* ew  = (const float*)d_in[2];
    const float* eW  = (const float*)d_in[3];
    const float* eb_ = (const float*)d_in[4];
    const float* mW1 = (const float*)d_in[5];
    const float* mb1 = (const float*)d_in[6];
    const float* mW2 = (const float*)d_in[7];
    const float* mb2 = (const float*)d_in[8];
    const float* aW1 = (const float*)d_in[9];
    const float* ab1 = (const float*)d_in[10];
    const float* aW2 = (const float*)d_in[11];
    const float* ab2 = (const float*)d_in[12];
    const float* uW1 = (const float*)d_in[13];
    const float* ub1 = (const float*)d_in[14];
    const float* uW2 = (const float*)d_in[15];
    const float* ub2 = (const float*)d_in[16];
    const float* hW  = (const float*)d_in[17];
    const float* hb  = (const float*)d_in[18];

    int N = in_sizes[0] / F;
    int E = in_sizes[2];
    const int* row = ei;
    const int* col = ei + E;

    size_t Nr = ((size_t)N + 3) & ~(size_t)3;
    size_t Er = ((size_t)E + 3) & ~(size_t)3;
    int NB = (E + 1023) / 1024;           // blocks in bucket passes
    int BS = (N + NBKT - 1) / NBKT;       // nodes per bucket
    size_t M = (size_t)NBKT * NB;         // bucket-count array size
    size_t Mr = (M + 3) & ~(size_t)3;

    // pick smallest chunk count k (chunks = 128/k buckets) that fits ws
    int k = 8;
    size_t ce = 0;
    const int kcand[4] = {1, 2, 4, 8};
    for (int i = 0; i < 4; ++i) {
        int kk = kcand[i];
        size_t c = ((size_t)(E / kk) + 16384 + 3) & ~(size_t)3;
        size_t elems = Nr * 32        // xh (f16)
                     + Nr * 32        // agg (f16)
                     + Nr             // fwsum
                     + 64             // serp
                     + 3 * Nr         // deg, startp, cursor
                     + 256            // bsum
                     + 8192 + 4096    // msgB, attB
                     + 8192 + 128     // M2U, mbu
                     + 12288          // updB
                     + 2 * Mr         // cnt, off
                     + 4 * Er         // edata (int4)
                     + c * 32;        // hfw (bf16)
        if (elems * 4 <= ws_size || i == 3) { k = kk; ce = c; break; }
    }

    _Float16* xh  = (_Float16*)d_ws;                  // Nr*64 f16
    _Float16* agg = xh + Nr * 64;                     // Nr*64 f16
    float* fwsum  = (float*)(agg + Nr * 64);          // Nr
    unsigned int* serp = (unsigned int*)(fwsum + Nr); // 64
    int*   deg    = (int*)(serp + 64);                // Nr
    int*   startp = deg + Nr;                         // Nr
    int*   cursor = startp + Nr;                      // Nr
    int*   bsum   = cursor + Nr;                      // 256
    f16x8* msgB   = (f16x8*)(bsum + 256);             // 2048 units
    f16x8* attB   = msgB + 2048;                      // 1024 units
    float* M2U    = (float*)(attB + 1024);            // 8192
    float* mbu    = M2U + 8192;                       // 128
    f16x8* updB   = (f16x8*)(mbu + 128);              // 3072 units
    int*   cnt    = (int*)(updB + 3072);              // Mr
    int*   off    = cnt + Mr;                         // Mr
    int4*  edata  = (int4*)(off + Mr);                // Er int4
    __hip_bfloat16* hfw = (__hip_bfloat16*)(edata + Er);  // ce*H bf16

    int nb_n = (N + 255) / 256;
    int nb_e = (E + 255) / 256;
    int nb_scan = (N + 1023) / 1024;     // <=256 (N<=262144)
    int nb_scanM = (int)((M + 1023) / 1024);  // <=256 (E<=2.09M)

    // ---- counting-sort metadata + coarse bucket partition ----
    hipMemsetAsync(deg, 0, (size_t)N * sizeof(int), stream);
    hist_kernel<<<nb_e, 256, 0, stream>>>(col, deg, E);
    scan1_kernel<<<nb_scan, 256, 0, stream>>>(deg, startp, bsum, N);
    scan2_kernel<<<1, 256, 0, stream>>>(bsum, nb_scan);
    scan3_kernel<<<nb_n, 256, 0, stream>>>(startp, bsum, cursor, N);

    count_bucket_kernel<<<NB, 256, 0, stream>>>(col, cnt, E, NB, BS);
    scan1_kernel<<<nb_scanM, 256, 0, stream>>>(cnt, off, bsum, (int)M);
    scan2_kernel<<<1, 256, 0, stream>>>(bsum, nb_scanM);
    scan3_kernel<<<(int)((M + 255) / 256), 256, 0, stream>>>(off, bsum, off, (int)M);
    place_kernel<<<NB, 256, 0, stream>>>(row, col, ew, off, edata, E, NB, BS);

    packfrag_kernel<<<12, 256, 0, stream>>>(mW1, aW1, msgB, attB);
    prep_update_kernel<<<32, 256, 0, stream>>>(mW2, mb2, uW1, M2U, mbu);
    packfrag_upd_kernel<<<12, 256, 0, stream>>>(uW1, M2U, uW2, updB);
    embed_kernel<<<nb_n, 256, 0, stream>>>(nf, eW, eb_, xh, N);

    int npc = (NBKT / k) * BS;                 // nodes per chunk
    int nb_edge = (int)((ce + 255) / 256);     // 4 waves/block, 64 edges/wave
    int nwaves_n = (N + 63) / 64;
    for (int l = 0; l < 2; ++l) {
        hipMemsetAsync(fwsum, 0, (size_t)N * sizeof(float), stream);
        for (int c = 0; c < k; ++c) {
            int nlo = c * npc;
            int nhi = (c == k - 1) ? N : (nlo + npc < N ? nlo + npc : N);
            if (nlo >= N) break;
            int nb_gath = (nhi - nlo + 3) / 4;
            edge_mfma_kernel<<<nb_edge, 256, 0, stream>>>(
                xh, edata, cursor, startp,
                msgB + (size_t)l * 16 * 64,
                attB + (size_t)l * 8 * 64,
                mb1 + (size_t)l * H,
                ab1 + (size_t)l * (H / 2),
                aW2 + (size_t)l * (H / 2), ab2 + (size_t)l,
                hfw, fwsum, nlo, nhi, N, E);
            gather_kernel<<<nb_gath, 256, 0, stream>>>(
                hfw, startp, deg, cursor, agg, nlo, nhi, N, E);
        }
        update_mfma_kernel<<<(nwaves_n + 3) / 4, 256, 0, stream>>>(
            xh, agg, fwsum,
            updB + (size_t)l * 24 * 64,
            mbu + (size_t)l * 64,
            ub1 + (size_t)l * H, ub2 + (size_t)l * H, N);
    }

    hipMemsetAsync(serp, 0, 64 * sizeof(unsigned int), stream);
    max_kernel<<<256, 256, 0, stream>>>(xh, serp, N);
    head_kernel<<<1, 64, 0, stream>>>(serp, hW, hb, (float*)d_out);
}

// Round 14
// 764.464 us; speedup vs baseline: 1.0776x; 1.0776x over previous
//
#include <hip/hip_runtime.h>
#include <hip/hip_bf16.h>
#include <math.h>

#define H 64
#define F 18
#define NBKT 512   // buckets for coarse partition (bucket ~ E/512 edges)

typedef _Float16 f16x8 __attribute__((ext_vector_type(8)));
typedef float f32x4 __attribute__((ext_vector_type(4)));

// ---------------------------------------------------------------- embed ----
__global__ __launch_bounds__(256) void embed_kernel(
    const float* __restrict__ nf, const float* __restrict__ W,
    const float* __restrict__ b, _Float16* __restrict__ xh, int N)
{
    int n = blockIdx.x * 256 + threadIdx.x;
    if (n >= N) return;
    float acc[H];
#pragma unroll
    for (int j = 0; j < H; ++j) acc[j] = b[j];
    const float* f = nf + (long)n * F;
#pragma unroll
    for (int i = 0; i < F; ++i) {
        float c = f[i];
        const float* w = W + i * H;
#pragma unroll
        for (int j = 0; j < H; ++j) acc[j] += c * w[j];
    }
    union { uint4 v[8]; _Float16 h[64]; } O;
#pragma unroll
    for (int j = 0; j < H; ++j) O.h[j] = (_Float16)fmaxf(acc[j], 0.f);
    uint4* xo = (uint4*)(xh + (size_t)n * H);
#pragma unroll
    for (int i = 0; i < 8; ++i) xo[i] = O.v[i];
}

// ------------------------------------------------- B-fragment prepack -----
__global__ __launch_bounds__(256) void packfrag_kernel(
    const float* __restrict__ mW1, const float* __restrict__ aW1,
    f16x8* __restrict__ msgB, f16x8* __restrict__ attB)
{
    int t = blockIdx.x * 256 + threadIdx.x;  // 0..3071
    if (t >= 3072) return;
    int lane = t & 63;
    int frag = t >> 6;            // 0..47
    int l = frag / 24, f = frag % 24;
    int quad = lane >> 4, l15 = lane & 15;
    f16x8 v;
    if (f < 16) {
        int nt = f >> 2, kk = f & 3;
        const float* W = mW1 + (size_t)l * 128 * 64;
#pragma unroll
        for (int j = 0; j < 8; ++j) {
            int k = kk * 32 + quad * 8 + j;
            v[j] = (_Float16)W[k * 64 + nt * 16 + l15];
        }
        msgB[((size_t)l * 16 + f) * 64 + lane] = v;
    } else {
        int f2 = f - 16;
        int nt = f2 >> 2, kk = f2 & 3;
        const float* W = aW1 + (size_t)l * 128 * 32;
#pragma unroll
        for (int j = 0; j < 8; ++j) {
            int k = kk * 32 + quad * 8 + j;
            v[j] = (_Float16)W[k * 32 + nt * 16 + l15];
        }
        attB[((size_t)l * 8 + f2) * 64 + lane] = v;
    }
}

// ---------------------------------------------- update-path precompute ----
__global__ __launch_bounds__(256) void prep_update_kernel(
    const float* __restrict__ mW2, const float* __restrict__ mb2,
    const float* __restrict__ uW1,
    float* __restrict__ M2U, float* __restrict__ mbu)
{
    int t = blockIdx.x * 256 + threadIdx.x;  // 0..8191
    if (t >= 2 * 64 * 64) return;
    int l = t >> 12, r = t & 4095;
    int i = r >> 6, j = r & 63;
    const float* W2 = mW2 + (size_t)l * 4096;
    const float* U1b = uW1 + (size_t)l * 8192 + 4096;  // rows 64..127
    float s = 0.f;
    for (int k = 0; k < 64; ++k) s += W2[i * 64 + k] * U1b[k * 64 + j];
    M2U[t] = s;
    if (i == 0) {
        float sb = 0.f;
        const float* b2 = mb2 + (size_t)l * 64;
        for (int k = 0; k < 64; ++k) sb += b2[k] * U1b[k * 64 + j];
        mbu[l * 64 + j] = sb;
    }
}

// g==1 (M2U) fragment rows PERMUTED: agg stored at pos=l15*4+nt (true col
// c = nt*16+l15), so k-th A element multiplies M2U row ((k&3)<<4)|(k>>2).
__global__ __launch_bounds__(256) void packfrag_upd_kernel(
    const float* __restrict__ uW1, const float* __restrict__ M2U,
    const float* __restrict__ uW2, f16x8* __restrict__ updB)
{
    int t = blockIdx.x * 256 + threadIdx.x;  // 0..3071
    if (t >= 3072) return;
    int lane = t & 63;
    int frag = t >> 6;  // 0..47
    int l = frag / 24, f = frag % 24;
    int quad = lane >> 4, l15 = lane & 15;
    int g = f >> 3, ff = f & 7;
    int nt = ff >> 1, kk = ff & 1;
    const float* src;
    if (g == 0)      src = uW1 + (size_t)l * 8192;       // rows 0..63
    else if (g == 1) src = M2U + (size_t)l * 4096;
    else             src = uW2 + (size_t)l * 4096;
    f16x8 v;
#pragma unroll
    for (int j = 0; j < 8; ++j) {
        int k = kk * 32 + quad * 8 + j;
        int ks = (g == 1) ? (((k & 3) << 4) | (k >> 2)) : k;
        v[j] = (_Float16)src[ks * 64 + nt * 16 + l15];
    }
    updB[(size_t)frag * 64 + lane] = v;
}

// ----------------------------------------------- counting sort metadata ---
__global__ __launch_bounds__(256) void hist_kernel(
    const int* __restrict__ col, int* __restrict__ deg, int E)
{
    int e = blockIdx.x * 256 + threadIdx.x;
    if (e < E) atomicAdd(deg + col[e], 1);
}

__global__ __launch_bounds__(256) void scan1_kernel(
    const int* __restrict__ deg, int* __restrict__ part,
    int* __restrict__ bsum, int N)
{
    __shared__ int lds[256];
    int t = threadIdx.x;
    int base = blockIdx.x * 1024 + t * 4;
    int v[4];
#pragma unroll
    for (int s = 0; s < 4; ++s) v[s] = (base + s < N) ? deg[base + s] : 0;
    int sum = v[0] + v[1] + v[2] + v[3];
    lds[t] = sum;
    __syncthreads();
    for (int off = 1; off < 256; off <<= 1) {
        int xv = (t >= off) ? lds[t - off] : 0;
        __syncthreads();
        lds[t] += xv;
        __syncthreads();
    }
    int excl = lds[t] - sum;
    if (t == 255) bsum[blockIdx.x] = lds[255];
    int p = excl;
#pragma unroll
    for (int s = 0; s < 4; ++s) {
        if (base + s < N) part[base + s] = p;
        p += v[s];
    }
}

__global__ __launch_bounds__(256) void scan2_kernel(int* __restrict__ bsum, int nb)
{
    __shared__ int lds[256];
    int t = threadIdx.x;
    int v = (t < nb) ? bsum[t] : 0;
    lds[t] = v;
    __syncthreads();
    for (int off = 1; off < 256; off <<= 1) {
        int xv = (t >= off) ? lds[t - off] : 0;
        __syncthreads();
        lds[t] += xv;
        __syncthreads();
    }
    if (t < nb) bsum[t] = lds[t] - v;
}

__global__ __launch_bounds__(256) void scan3_kernel(
    int* __restrict__ part, const int* __restrict__ bsum, int N)
{
    int i = blockIdx.x * 256 + threadIdx.x;
    if (i >= N) return;
    part[i] = part[i] + bsum[i >> 10];
}

// ----------------------------------------- coarse bucket partition --------
__global__ __launch_bounds__(256) void count_bucket_kernel(
    const int* __restrict__ col, int* __restrict__ cnt,
    int E, int NB, int BS)
{
    __shared__ int lc[NBKT];
    int t = threadIdx.x;
    for (int i = t; i < NBKT; i += 256) lc[i] = 0;
    __syncthreads();
#pragma unroll
    for (int s = 0; s < 16; ++s) {
        int e = blockIdx.x * 4096 + s * 256 + t;
        if (e < E) atomicAdd(lc + (unsigned)col[e] / (unsigned)BS, 1);
    }
    __syncthreads();
    for (int i = t; i < NBKT; i += 256)
        cnt[(size_t)i * NB + blockIdx.x] = lc[i];
}

__global__ __launch_bounds__(256) void place_kernel(
    const int* __restrict__ row, const int* __restrict__ col,
    const float* __restrict__ ew, const int* __restrict__ off,
    int4* __restrict__ edata, int E, int NB, int BS)
{
    __shared__ int lc[NBKT];
    int t = threadIdx.x;
    for (int i = t; i < NBKT; i += 256) lc[i] = 0;
    __syncthreads();
#pragma unroll
    for (int s = 0; s < 16; ++s) {
        int e = blockIdx.x * 4096 + s * 256 + t;
        if (e < E) {
            int cv = col[e];
            int c = (unsigned)cv / (unsigned)BS;
            int r = atomicAdd(lc + c, 1);
            int pos = off[(size_t)c * NB + blockIdx.x] + r;
            edata[pos] = make_int4(row[e], cv, __float_as_int(ew[e]), 0);
        }
    }
}

// ------------------------------------------- per-bucket in-place sort -----
// One block per bucket (mean E/512 ~ 3125 edges, reg cap 4096 = +17sigma
// for uniform cols). Edges->registers, LDS hist over the bucket's BS-node
// range, 512-entry LDS scan, barrier, place back node-sorted. Globally:
// base + local_prefix(n) == startp[n].
__global__ __launch_bounds__(256) void bucket_sort_kernel(
    int4* __restrict__ edata, const int* __restrict__ off,
    int NB, int BS, int E)
{
    __shared__ int hist[512];
    __shared__ int psum[256];
    int b = blockIdx.x;
    int t = threadIdx.x;
    int base = off[(size_t)b * NB];
    int end  = (b + 1 < NBKT) ? off[(size_t)(b + 1) * NB] : E;
    int cnt = end - base;
    int nlo = b * BS;
    hist[t] = 0; hist[256 + t] = 0;
    __syncthreads();

    int4 regs[16];
#pragma unroll
    for (int ii = 0; ii < 16; ++ii) {
        int i = t + ii * 256;
        if (i < cnt) {
            regs[ii] = edata[base + i];
            atomicAdd(hist + (regs[ii].y - nlo), 1);
        }
    }
    __syncthreads();

    int a0 = hist[2 * t], a1 = hist[2 * t + 1];
    int s = a0 + a1;
    psum[t] = s;
    __syncthreads();
    for (int o = 1; o < 256; o <<= 1) {
        int xv = (t >= o) ? psum[t - o] : 0;
        __syncthreads();
        psum[t] += xv;
        __syncthreads();
    }
    int excl = psum[t] - s;
    hist[2 * t] = excl;
    hist[2 * t + 1] = excl + a0;
    __syncthreads();

#pragma unroll
    for (int ii = 0; ii < 16; ++ii) {
        int i = t + ii * 256;
        if (i < cnt) {
            int pos = atomicAdd(hist + (regs[ii].y - nlo), 1);
            edata[base + pos] = regs[ii];
        }
    }
}

// ----------------------------------------------------------------- edge ----
// Fully node-sorted edata; slot = own index -> SEQUENTIAL full-line hfw
// writes (streaming), no atomics. e0/e1 derived from startp on device.
__global__ __launch_bounds__(256) void edge_mfma_kernel(
    const _Float16* __restrict__ xh,
    const int4* __restrict__ edata, const int* __restrict__ startp,
    const f16x8* __restrict__ msgB,  // [16][64] this layer
    const f16x8* __restrict__ attB,  // [8][64]
    const float* __restrict__ b1, const float* __restrict__ ab1,
    const float* __restrict__ aW2, const float* __restrict__ ab2,
    __hip_bfloat16* __restrict__ hfw, float* __restrict__ fwbuf,
    int nlo, int nhi, int N, int E)
{
    int e0 = startp[nlo];
    int e1 = (nhi < N) ? startp[nhi] : E;
    int ecnt = e1 - e0;
    int wid = (blockIdx.x * 256 + threadIdx.x) >> 6;
    int lane = threadIdx.x & 63;
    int wbase = wid * 64;
    if (wbase >= ecnt) return;
    int quad = lane >> 4, l15 = lane & 15;

    f16x8 mb[4][4], ab[2][4];
#pragma unroll
    for (int nt = 0; nt < 4; ++nt)
#pragma unroll
        for (int kk = 0; kk < 4; ++kk)
            mb[nt][kk] = msgB[(nt * 4 + kk) * 64 + lane];
#pragma unroll
    for (int nt = 0; nt < 2; ++nt)
#pragma unroll
        for (int kk = 0; kk < 4; ++kk)
            ab[nt][kk] = attB[(nt * 4 + kk) * 64 + lane];

    float ab1v0 = ab1[l15], ab1v1 = ab1[16 + l15];
    float aw20 = aW2[l15], aw21 = aW2[16 + l15];
    float ab2v = ab2[0];
    float bm[4];
#pragma unroll
    for (int nt = 0; nt < 4; ++nt) bm[nt] = b1[nt * 16 + l15];

    for (int mt = 0; mt < 4; ++mt) {
        int lea = wbase + mt * 16 + l15;
        bool av = lea < ecnt;
        int leac = av ? lea : ecnt - 1;
        int4 ed = edata[e0 + leac];
        int rowv = ed.x, colv = ed.y;
        float ewl = __int_as_float(ed.z);
        float ewc[4];
#pragma unroll
        for (int r = 0; r < 4; ++r) ewc[r] = __shfl(ewl, quad * 4 + r);

        const f16x8* rowp = (const f16x8*)(xh + (size_t)rowv * H);
        const f16x8* colp = (const f16x8*)(xh + (size_t)colv * H);
        f16x8 A[4];
        A[0] = rowp[quad];
        A[1] = rowp[4 + quad];
        A[2] = colp[quad];
        A[3] = colp[4 + quad];

        f32x4 ac0 = {0.f, 0.f, 0.f, 0.f}, ac1 = {0.f, 0.f, 0.f, 0.f};
#pragma unroll
        for (int kk = 0; kk < 4; ++kk) {
            ac0 = __builtin_amdgcn_mfma_f32_16x16x32_f16(A[kk], ab[0][kk], ac0, 0, 0, 0);
            ac1 = __builtin_amdgcn_mfma_f32_16x16x32_f16(A[kk], ab[1][kk], ac1, 0, 0, 0);
        }
        float p[4];
#pragma unroll
        for (int r = 0; r < 4; ++r) {
            float v0 = fmaxf(ac0[r] + ab1v0, 0.f) * aw20;
            float v1 = fmaxf(ac1[r] + ab1v1, 0.f) * aw21;
            p[r] = v0 + v1;
        }
#pragma unroll
        for (int off = 1; off < 16; off <<= 1) {
#pragma unroll
            for (int r = 0; r < 4; ++r) p[r] += __shfl_xor(p[r], off);
        }
        float fw[4];
#pragma unroll
        for (int r = 0; r < 4; ++r) {
            int leg = wbase + mt * 16 + quad * 4 + r;
            float ewv = (leg < ecnt) ? ewc[r] : 0.f;
            fw[r] = ewv / (1.f + __expf(-(p[r] + ab2v)));
        }

        f32x4 mc[4];
#pragma unroll
        for (int nt = 0; nt < 4; ++nt) {
            f32x4 cc = {0.f, 0.f, 0.f, 0.f};
#pragma unroll
            for (int kk = 0; kk < 4; ++kk)
                cc = __builtin_amdgcn_mfma_f32_16x16x32_f16(A[kk], mb[nt][kk], cc, 0, 0, 0);
            mc[nt] = cc;
        }

#pragma unroll
        for (int r = 0; r < 4; ++r) {
            int leg = wbase + mt * 16 + quad * 4 + r;
            if (leg < ecnt) {
                union { unsigned short u[4]; uint2 v; } pk;
#pragma unroll
                for (int nt = 0; nt < 4; ++nt) {
                    __hip_bfloat16 hb =
                        __float2bfloat16(fmaxf(mc[nt][r] + bm[nt], 0.f) * fw[r]);
                    pk.u[nt] = *reinterpret_cast<unsigned short*>(&hb);
                }
                *(uint2*)(hfw + (size_t)leg * H + l15 * 4) = pk.v;
                if (l15 == 0) fwbuf[leg] = fw[r];
            }
        }
    }
}

// --------------------------------------------------------------- gather ----
__global__ __launch_bounds__(256) void gather_kernel(
    const __hip_bfloat16* __restrict__ hfw, const float* __restrict__ fwbuf,
    const int* __restrict__ startp, const int* __restrict__ deg,
    _Float16* __restrict__ agg, float* __restrict__ fwsum,
    int nlo, int nhi, int N, int E)
{
    int wid = (blockIdx.x * 256 + threadIdx.x) >> 6;
    int lane = threadIdx.x & 63;
    int n = nlo + wid;
    if (n >= nhi) return;
    int e0 = startp[nlo];
    int s = startp[n];
    int d = deg[n];
    int base = s - e0;
    float acc = 0.f;
    const __hip_bfloat16* hp = hfw + (size_t)base * H + lane;
    for (int i = 0; i < d; ++i) acc += __bfloat162float(hp[(size_t)i * H]);
    float fwl = 0.f;
    for (int i = lane; i < d; i += 64) fwl += fwbuf[base + i];
#pragma unroll
    for (int off = 32; off > 0; off >>= 1) fwl += __shfl_down(fwl, off);
    agg[(size_t)n * H + lane] = (_Float16)acc;
    if (lane == 0) fwsum[n] = fwl;
}

// --------------------------------------------------------------- update ----
__global__ __launch_bounds__(256, 2) void update_mfma_kernel(
    _Float16* __restrict__ xh, const _Float16* __restrict__ agg,
    const float* __restrict__ fwsum,
    const f16x8* __restrict__ Bfrag,  // [24][64] this layer
    const float* __restrict__ mbu,    // [64]
    const float* __restrict__ ub1, const float* __restrict__ ub2, int N)
{
    __shared__ __align__(16) _Float16 hlds[4][16 * 80];
    int wib = threadIdx.x >> 6;
    int lane = threadIdx.x & 63;
    int wid = (blockIdx.x * 256 + threadIdx.x) >> 6;
    int quad = lane >> 4, l15 = lane & 15;
    int nbase = wid * 64;
    if (nbase >= N) return;

    f16x8 Bu[8], Bm[8], Bw[8];
#pragma unroll
    for (int i = 0; i < 8; ++i) {
        Bu[i] = Bfrag[i * 64 + lane];
        Bm[i] = Bfrag[(8 + i) * 64 + lane];
        Bw[i] = Bfrag[(16 + i) * 64 + lane];
    }
    float mbuv[4], b1v[4], b2v[4];
#pragma unroll
    for (int nt = 0; nt < 4; ++nt) {
        mbuv[nt] = mbu[nt * 16 + l15];
        b1v[nt] = ub1[nt * 16 + l15];
        b2v[nt] = ub2[nt * 16 + l15];
    }

    for (int mt = 0; mt < 4; ++mt) {
        int na = nbase + mt * 16 + l15;
        if (na >= N) na = N - 1;
        const f16x8* xrow = (const f16x8*)(xh + (size_t)na * H);
        f16x8 Ax[2];
        Ax[0] = xrow[quad];
        Ax[1] = xrow[4 + quad];
        const f16x8* arow = (const f16x8*)(agg + (size_t)na * H);
        f16x8 Aa[2];
        Aa[0] = arow[quad];
        Aa[1] = arow[4 + quad];

        f32x4 Cx[4], Ca[4];
#pragma unroll
        for (int nt = 0; nt < 4; ++nt) {
            f32x4 cx = {0.f, 0.f, 0.f, 0.f}, ca = {0.f, 0.f, 0.f, 0.f};
#pragma unroll
            for (int kk = 0; kk < 2; ++kk) {
                cx = __builtin_amdgcn_mfma_f32_16x16x32_f16(Ax[kk], Bu[nt * 2 + kk], cx, 0, 0, 0);
                ca = __builtin_amdgcn_mfma_f32_16x16x32_f16(Aa[kk], Bm[nt * 2 + kk], ca, 0, 0, 0);
            }
            Cx[nt] = cx; Ca[nt] = ca;
        }

        int noder = nbase + mt * 16 + quad * 4;
        float fws_r[4], inv_r[4];
#pragma unroll
        for (int r = 0; r < 4; ++r) {
            int ng = noder + r; if (ng >= N) ng = N - 1;
            float fws = fwsum[ng];
            fws_r[r] = fws;
            inv_r[r] = 1.f / fmaxf(fws, 1e-6f);
        }

#pragma unroll
        for (int nt = 0; nt < 4; ++nt) {
#pragma unroll
            for (int r = 0; r < 4; ++r) {
                float hv = fmaxf(Cx[nt][r] + inv_r[r] * Ca[nt][r]
                                 + fws_r[r] * inv_r[r] * mbuv[nt] + b1v[nt], 0.f);
                hlds[wib][(quad * 4 + r) * 80 + nt * 16 + l15] = (_Float16)hv;
            }
        }
        __asm__ __volatile__("s_waitcnt lgkmcnt(0)" ::: "memory");
        f16x8 Ah[2];
        Ah[0] = *(const f16x8*)&hlds[wib][l15 * 80 + quad * 8];
        Ah[1] = *(const f16x8*)&hlds[wib][l15 * 80 + 32 + quad * 8];
        __asm__ __volatile__("s_waitcnt lgkmcnt(0)" ::: "memory");

        f32x4 C2[4];
#pragma unroll
        for (int nt = 0; nt < 4; ++nt) {
            f32x4 cc = {0.f, 0.f, 0.f, 0.f};
#pragma unroll
            for (int kk = 0; kk < 2; ++kk)
                cc = __builtin_amdgcn_mfma_f32_16x16x32_f16(Ah[kk], Bw[nt * 2 + kk], cc, 0, 0, 0);
            C2[nt] = cc;
        }

#pragma unroll
        for (int r = 0; r < 4; ++r) {
            int ng = noder + r;
            if (ng < N) {
#pragma unroll
                for (int nt = 0; nt < 4; ++nt) {
                    size_t idx = (size_t)ng * H + nt * 16 + l15;
                    float xo = (float)xh[idx];
                    xh[idx] = (_Float16)fmaxf(C2[nt][r] + b2v[nt] + xo, 0.f);
                }
            }
        }
    }
}

// ----------------------------------------------------------------- head ----
__global__ __launch_bounds__(256) void max_kernel(
    const _Float16* __restrict__ xh16, unsigned int* __restrict__ serp, int N)
{
    int j = threadIdx.x & (H - 1);
    int g = (blockIdx.x * 256 + threadIdx.x) >> 6;
    int stride = (gridDim.x * 256) >> 6;
    float m = 0.f;  // x >= 0 after relu
    for (int n = g; n < N; n += stride)
        m = fmaxf(m, (float)xh16[(size_t)n * H + j]);
    atomicMax(serp + j, __float_as_uint(m));
}

__global__ void head_kernel(const unsigned int* __restrict__ serp,
                            const float* __restrict__ hW,
                            const float* __restrict__ hb,
                            float* __restrict__ out)
{
    int j = threadIdx.x;  // 64 threads = 1 wave
    float v = __uint_as_float(serp[j]) * hW[j];
#pragma unroll
    for (int off = 32; off > 0; off >>= 1) v += __shfl_down(v, off);
    if (j == 0) out[0] = v + hb[0];
}

// --------------------------------------------------------------- launch ----
extern "C" void kernel_launch(void* const* d_in, const int* in_sizes, int n_in,
                              void* d_out, int out_size, void* d_ws, size_t ws_size,
                              hipStream_t stream)
{
    const float* nf  = (const float*)d_in[0];
    const int*   ei  = (const int*)d_in[1];
    const float* ew  = (const float*)d_in[2];
    const float* eW  = (const float*)d_in[3];
    const float* eb_ = (const float*)d_in[4];
    const float* mW1 = (const float*)d_in[5];
    const float* mb1 = (const float*)d_in[6];
    const float* mW2 = (const float*)d_in[7];
    const float* mb2 = (const float*)d_in[8];
    const float* aW1 = (const float*)d_in[9];
    const float* ab1 = (const float*)d_in[10];
    const float* aW2 = (const float*)d_in[11];
    const float* ab2 = (const float*)d_in[12];
    const float* uW1 = (const float*)d_in[13];
    const float* ub1 = (const float*)d_in[14];
    const float* uW2 = (const float*)d_in[15];
    const float* ub2 = (const float*)d_in[16];
    const float* hW  = (const float*)d_in[17];
    const float* hb  = (const float*)d_in[18];

    int N = in_sizes[0] / F;
    int E = in_sizes[2];
    const int* row = ei;
    const int* col = ei + E;

    size_t Nr = ((size_t)N + 3) & ~(size_t)3;
    size_t Er = ((size_t)E + 3) & ~(size_t)3;
    int NB = (E + 4095) / 4096;           // blocks in bucket passes
    int BS = (N + NBKT - 1) / NBKT;       // nodes per bucket
    size_t M = (size_t)NBKT * NB;         // bucket-count array size
    size_t Mr = (M + 3) & ~(size_t)3;

    // pick smallest chunk count k that fits ws
    int k = 8;
    size_t ce = 0;
    const int kcand[4] = {1, 2, 4, 8};
    for (int i = 0; i < 4; ++i) {
        int kk = kcand[i];
        size_t c = ((size_t)(E / kk) + 16384 + 3) & ~(size_t)3;
        size_t elems = Nr * 32 + Nr * 32 + Nr + 64 + 2 * Nr + 256
                     + 8192 + 4096 + 8192 + 128 + 12288
                     + 2 * Mr + 4 * Er + c + c * 32;
        if (elems * 4 <= ws_size || i == 3) { k = kk; ce = c; break; }
    }

    _Float16* xh  = (_Float16*)d_ws;                  // Nr*64 f16
    _Float16* agg = xh + Nr * 64;                     // Nr*64 f16
    float* fwsum  = (float*)(agg + Nr * 64);          // Nr
    unsigned int* serp = (unsigned int*)(fwsum + Nr); // 64
    int*   deg    = (int*)(serp + 64);                // Nr
    int*   startp = deg + Nr;                         // Nr
    int*   bsum   = startp + Nr;                      // 256
    f16x8* msgB   = (f16x8*)(bsum + 256);             // 2048 units
    f16x8* attB   = msgB + 2048;                      // 1024 units
    float* M2U    = (float*)(attB + 1024);            // 8192
    float* mbu    = M2U + 8192;                       // 128
    f16x8* updB   = (f16x8*)(mbu + 128);              // 3072 units
    int*   cnt    = (int*)(updB + 3072);              // Mr
    int*   off    = cnt + Mr;                         // Mr
    int4*  edata  = (int4*)(off + Mr);                // Er int4
    float* fwbuf  = (float*)(edata + Er);             // ce
    __hip_bfloat16* hfw = (__hip_bfloat16*)(fwbuf + ce);  // ce*H bf16

    int nb_n = (N + 255) / 256;
    int nb_e = (E + 255) / 256;
    int nb_scan = (N + 1023) / 1024;          // <=256 (N<=262144)
    int nb_scanM = (int)((M + 1023) / 1024);  // <=256

    hipMemsetAsync(deg, 0, (size_t)N * sizeof(int), stream);
    hist_kernel<<<nb_e, 256, 0, stream>>>(col, deg, E);
    scan1_kernel<<<nb_scan, 256, 0, stream>>>(deg, startp, bsum, N);
    scan2_kernel<<<1, 256, 0, stream>>>(bsum, nb_scan);
    scan3_kernel<<<nb_n, 256, 0, stream>>>(startp, bsum, N);

    count_bucket_kernel<<<NB, 256, 0, stream>>>(col, cnt, E, NB, BS);
    scan1_kernel<<<nb_scanM, 256, 0, stream>>>(cnt, off, bsum, (int)M);
    scan2_kernel<<<1, 256, 0, stream>>>(bsum, nb_scanM);
    scan3_kernel<<<(int)((M + 255) / 256), 256, 0, stream>>>(off, bsum, (int)M);
    place_kernel<<<NB, 256, 0, stream>>>(row, col, ew, off, edata, E, NB, BS);
    bucket_sort_kernel<<<NBKT, 256, 0, stream>>>(edata, off, NB, BS, E);

    packfrag_kernel<<<12, 256, 0, stream>>>(mW1, aW1, msgB, attB);
    prep_update_kernel<<<32, 256, 0, stream>>>(mW2, mb2, uW1, M2U, mbu);
    packfrag_upd_kernel<<<12, 256, 0, stream>>>(uW1, M2U, uW2, updB);
    embed_kernel<<<nb_n, 256, 0, stream>>>(nf, eW, eb_, xh, N);

    int npc = (N + k - 1) / k;
    int nb_edge = (int)((ce + 255) / 256);
    int nwaves_n = (N + 63) / 64;
    for (int l = 0; l < 2; ++l) {
        for (int c = 0; c < k; ++c) {
            int nlo = c * npc;
            if (nlo >= N) break;
            int nhi = (nlo + npc < N) ? nlo + npc : N;
            int nb_gath = (nhi - nlo + 3) / 4;
            edge_mfma_kernel<<<nb_edge, 256, 0, stream>>>(
                xh, edata, startp,
                msgB + (size_t)l * 16 * 64,
                attB + (size_t)l * 8 * 64,
                mb1 + (size_t)l * H,
                ab1 + (size_t)l * (H / 2),
                aW2 + (size_t)l * (H / 2), ab2 + (size_t)l,
                hfw, fwbuf, nlo, nhi, N, E);
            gather_kernel<<<nb_gath, 256, 0, stream>>>(
                hfw, fwbuf, startp, deg, agg, fwsum, nlo, nhi, N, E);
        }
        update_mfma_kernel<<<(nwaves_n + 3) / 4, 256, 0, stream>>>(
            xh, agg, fwsum,
            updB + (size_t)l * 24 * 64,
            mbu + (size_t)l * 64,
            ub1 + (size_t)l * H, ub2 + (size_t)l * H, N);
    }

    hipMemsetAsync(serp, 0, 64 * sizeof(unsigned int), stream);
    max_kernel<<<256, 256, 0, stream>>>(xh, serp, N);
    head_kernel<<<1, 64, 0, stream>>>(serp, hW, hb, (float*)d_out);
}

// Round 15
// 745.777 us; speedup vs baseline: 1.1046x; 1.0251x over previous
//
#include <hip/hip_runtime.h>
#include <hip/hip_bf16.h>
#include <math.h>

#define H 64
#define F 18
#define NBKT 512   // buckets for coarse partition (bucket ~ E/512 edges)

typedef _Float16 f16x8 __attribute__((ext_vector_type(8)));
typedef float f32x4 __attribute__((ext_vector_type(4)));

// ---------------------------------------------------------------- embed ----
__global__ __launch_bounds__(256) void embed_kernel(
    const float* __restrict__ nf, const float* __restrict__ W,
    const float* __restrict__ b, _Float16* __restrict__ xh, int N)
{
    int n = blockIdx.x * 256 + threadIdx.x;
    if (n >= N) return;
    float acc[H];
#pragma unroll
    for (int j = 0; j < H; ++j) acc[j] = b[j];
    const float* f = nf + (long)n * F;
#pragma unroll
    for (int i = 0; i < F; ++i) {
        float c = f[i];
        const float* w = W + i * H;
#pragma unroll
        for (int j = 0; j < H; ++j) acc[j] += c * w[j];
    }
    union { uint4 v[8]; _Float16 h[64]; } O;
#pragma unroll
    for (int j = 0; j < H; ++j) O.h[j] = (_Float16)fmaxf(acc[j], 0.f);
    uint4* xo = (uint4*)(xh + (size_t)n * H);
#pragma unroll
    for (int i = 0; i < 8; ++i) xo[i] = O.v[i];
}

// ------------------------------------------------- B-fragment prepack -----
__global__ __launch_bounds__(256) void packfrag_kernel(
    const float* __restrict__ mW1, const float* __restrict__ aW1,
    f16x8* __restrict__ msgB, f16x8* __restrict__ attB)
{
    int t = blockIdx.x * 256 + threadIdx.x;  // 0..3071
    if (t >= 3072) return;
    int lane = t & 63;
    int frag = t >> 6;            // 0..47
    int l = frag / 24, f = frag % 24;
    int quad = lane >> 4, l15 = lane & 15;
    f16x8 v;
    if (f < 16) {
        int nt = f >> 2, kk = f & 3;
        const float* W = mW1 + (size_t)l * 128 * 64;
#pragma unroll
        for (int j = 0; j < 8; ++j) {
            int k = kk * 32 + quad * 8 + j;
            v[j] = (_Float16)W[k * 64 + nt * 16 + l15];
        }
        msgB[((size_t)l * 16 + f) * 64 + lane] = v;
    } else {
        int f2 = f - 16;
        int nt = f2 >> 2, kk = f2 & 3;
        const float* W = aW1 + (size_t)l * 128 * 32;
#pragma unroll
        for (int j = 0; j < 8; ++j) {
            int k = kk * 32 + quad * 8 + j;
            v[j] = (_Float16)W[k * 32 + nt * 16 + l15];
        }
        attB[((size_t)l * 8 + f2) * 64 + lane] = v;
    }
}

// ---------------------------------------------- update-path precompute ----
__global__ __launch_bounds__(256) void prep_update_kernel(
    const float* __restrict__ mW2, const float* __restrict__ mb2,
    const float* __restrict__ uW1,
    float* __restrict__ M2U, float* __restrict__ mbu)
{
    int t = blockIdx.x * 256 + threadIdx.x;  // 0..8191
    if (t >= 2 * 64 * 64) return;
    int l = t >> 12, r = t & 4095;
    int i = r >> 6, j = r & 63;
    const float* W2 = mW2 + (size_t)l * 4096;
    const float* U1b = uW1 + (size_t)l * 8192 + 4096;  // rows 64..127
    float s = 0.f;
    for (int k = 0; k < 64; ++k) s += W2[i * 64 + k] * U1b[k * 64 + j];
    M2U[t] = s;
    if (i == 0) {
        float sb = 0.f;
        const float* b2 = mb2 + (size_t)l * 64;
        for (int k = 0; k < 64; ++k) sb += b2[k] * U1b[k * 64 + j];
        mbu[l * 64 + j] = sb;
    }
}

// g==1 (M2U) fragment rows PERMUTED: agg stored at pos=l15*4+nt (true col
// c = nt*16+l15), so k-th A element multiplies M2U row ((k&3)<<4)|(k>>2).
__global__ __launch_bounds__(256) void packfrag_upd_kernel(
    const float* __restrict__ uW1, const float* __restrict__ M2U,
    const float* __restrict__ uW2, f16x8* __restrict__ updB)
{
    int t = blockIdx.x * 256 + threadIdx.x;  // 0..3071
    if (t >= 3072) return;
    int lane = t & 63;
    int frag = t >> 6;  // 0..47
    int l = frag / 24, f = frag % 24;
    int quad = lane >> 4, l15 = lane & 15;
    int g = f >> 3, ff = f & 7;
    int nt = ff >> 1, kk = ff & 1;
    const float* src;
    if (g == 0)      src = uW1 + (size_t)l * 8192;       // rows 0..63
    else if (g == 1) src = M2U + (size_t)l * 4096;
    else             src = uW2 + (size_t)l * 4096;
    f16x8 v;
#pragma unroll
    for (int j = 0; j < 8; ++j) {
        int k = kk * 32 + quad * 8 + j;
        int ks = (g == 1) ? (((k & 3) << 4) | (k >> 2)) : k;
        v[j] = (_Float16)src[ks * 64 + nt * 16 + l15];
    }
    updB[(size_t)frag * 64 + lane] = v;
}

// ----------------------------------------------- counting sort metadata ---
__global__ __launch_bounds__(256) void hist_kernel(
    const int* __restrict__ col, int* __restrict__ deg, int E)
{
    int e = blockIdx.x * 256 + threadIdx.x;
    if (e < E) atomicAdd(deg + col[e], 1);
}

__global__ __launch_bounds__(256) void scan1_kernel(
    const int* __restrict__ deg, int* __restrict__ part,
    int* __restrict__ bsum, int N)
{
    __shared__ int lds[256];
    int t = threadIdx.x;
    int base = blockIdx.x * 1024 + t * 4;
    int v[4];
#pragma unroll
    for (int s = 0; s < 4; ++s) v[s] = (base + s < N) ? deg[base + s] : 0;
    int sum = v[0] + v[1] + v[2] + v[3];
    lds[t] = sum;
    __syncthreads();
    for (int off = 1; off < 256; off <<= 1) {
        int xv = (t >= off) ? lds[t - off] : 0;
        __syncthreads();
        lds[t] += xv;
        __syncthreads();
    }
    int excl = lds[t] - sum;
    if (t == 255) bsum[blockIdx.x] = lds[255];
    int p = excl;
#pragma unroll
    for (int s = 0; s < 4; ++s) {
        if (base + s < N) part[base + s] = p;
        p += v[s];
    }
}

__global__ __launch_bounds__(256) void scan2_kernel(int* __restrict__ bsum, int nb)
{
    __shared__ int lds[256];
    int t = threadIdx.x;
    int v = (t < nb) ? bsum[t] : 0;
    lds[t] = v;
    __syncthreads();
    for (int off = 1; off < 256; off <<= 1) {
        int xv = (t >= off) ? lds[t - off] : 0;
        __syncthreads();
        lds[t] += xv;
        __syncthreads();
    }
    if (t < nb) bsum[t] = lds[t] - v;
}

__global__ __launch_bounds__(256) void scan3_kernel(
    int* __restrict__ part, const int* __restrict__ bsum, int N)
{
    int i = blockIdx.x * 256 + threadIdx.x;
    if (i >= N) return;
    part[i] = part[i] + bsum[i >> 10];
}

// ----------------------------------------- coarse bucket partition --------
__global__ __launch_bounds__(256) void count_bucket_kernel(
    const int* __restrict__ col, int* __restrict__ cnt,
    int E, int NB, int BS)
{
    __shared__ int lc[NBKT];
    int t = threadIdx.x;
    for (int i = t; i < NBKT; i += 256) lc[i] = 0;
    __syncthreads();
#pragma unroll
    for (int s = 0; s < 16; ++s) {
        int e = blockIdx.x * 4096 + s * 256 + t;
        if (e < E) atomicAdd(lc + (unsigned)col[e] / (unsigned)BS, 1);
    }
    __syncthreads();
    for (int i = t; i < NBKT; i += 256)
        cnt[(size_t)i * NB + blockIdx.x] = lc[i];
}

__global__ __launch_bounds__(256) void place_kernel(
    const int* __restrict__ row, const int* __restrict__ col,
    const float* __restrict__ ew, const int* __restrict__ off,
    int4* __restrict__ edata, int E, int NB, int BS)
{
    __shared__ int lc[NBKT];
    int t = threadIdx.x;
    for (int i = t; i < NBKT; i += 256) lc[i] = 0;
    __syncthreads();
#pragma unroll
    for (int s = 0; s < 16; ++s) {
        int e = blockIdx.x * 4096 + s * 256 + t;
        if (e < E) {
            int cv = col[e];
            int c = (unsigned)cv / (unsigned)BS;
            int r = atomicAdd(lc + c, 1);
            int pos = off[(size_t)c * NB + blockIdx.x] + r;
            edata[pos] = make_int4(row[e], cv, __float_as_int(ew[e]), 0);
        }
    }
}

// ------------------------------------------- per-bucket in-place sort -----
__global__ __launch_bounds__(256) void bucket_sort_kernel(
    int4* __restrict__ edata, const int* __restrict__ off,
    int NB, int BS, int E)
{
    __shared__ int hist[512];
    __shared__ int psum[256];
    int b = blockIdx.x;
    int t = threadIdx.x;
    int base = off[(size_t)b * NB];
    int end  = (b + 1 < NBKT) ? off[(size_t)(b + 1) * NB] : E;
    int cnt = end - base;
    int nlo = b * BS;
    hist[t] = 0; hist[256 + t] = 0;
    __syncthreads();

    int4 regs[16];
#pragma unroll
    for (int ii = 0; ii < 16; ++ii) {
        int i = t + ii * 256;
        if (i < cnt) {
            regs[ii] = edata[base + i];
            atomicAdd(hist + (regs[ii].y - nlo), 1);
        }
    }
    __syncthreads();

    int a0 = hist[2 * t], a1 = hist[2 * t + 1];
    int s = a0 + a1;
    psum[t] = s;
    __syncthreads();
    for (int o = 1; o < 256; o <<= 1) {
        int xv = (t >= o) ? psum[t - o] : 0;
        __syncthreads();
        psum[t] += xv;
        __syncthreads();
    }
    int excl = psum[t] - s;
    hist[2 * t] = excl;
    hist[2 * t + 1] = excl + a0;
    __syncthreads();

#pragma unroll
    for (int ii = 0; ii < 16; ++ii) {
        int i = t + ii * 256;
        if (i < cnt) {
            int pos = atomicAdd(hist + (regs[ii].y - nlo), 1);
            edata[base + pos] = regs[ii];
        }
    }
}

// ----------------------------------------------------------------- edge ----
// Node-sorted edata; slot = own index -> sequential streaming hfw writes.
// R15: (1) edge relabel swap(m)=transpose-4x4 so each store instruction
// writes 4 CONTIGUOUS lines; (2) single edata load/lane + __shfl per mt
// (kills the per-mt load->addr->load chain; all A-loads can hoist);
// (3) biases folded into MFMA C-init.
__global__ __launch_bounds__(256) void edge_mfma_kernel(
    const _Float16* __restrict__ xh,
    const int4* __restrict__ edata, const int* __restrict__ startp,
    const f16x8* __restrict__ msgB,  // [16][64] this layer
    const f16x8* __restrict__ attB,  // [8][64]
    const float* __restrict__ b1, const float* __restrict__ ab1,
    const float* __restrict__ aW2, const float* __restrict__ ab2,
    __hip_bfloat16* __restrict__ hfw, float* __restrict__ fwbuf,
    int nlo, int nhi, int N, int E)
{
    int e0 = startp[nlo];
    int e1 = (nhi < N) ? startp[nhi] : E;
    int ecnt = e1 - e0;
    int wid = (blockIdx.x * 256 + threadIdx.x) >> 6;
    int lane = threadIdx.x & 63;
    int wbase = wid * 64;
    if (wbase >= ecnt) return;
    int quad = lane >> 4, l15 = lane & 15;

    f16x8 mb[4][4], ab[2][4];
#pragma unroll
    for (int nt = 0; nt < 4; ++nt)
#pragma unroll
        for (int kk = 0; kk < 4; ++kk)
            mb[nt][kk] = msgB[(nt * 4 + kk) * 64 + lane];
#pragma unroll
    for (int nt = 0; nt < 2; ++nt)
#pragma unroll
        for (int kk = 0; kk < 4; ++kk)
            ab[nt][kk] = attB[(nt * 4 + kk) * 64 + lane];

    float ab1v0 = ab1[l15], ab1v1 = ab1[16 + l15];
    float aw20 = aW2[l15], aw21 = aW2[16 + l15];
    float ab2v = ab2[0];
    float bm[4];
#pragma unroll
    for (int nt = 0; nt < 4; ++nt) bm[nt] = b1[nt * 16 + l15];

    // one edata load per lane (own edge); everything else via shuffles
    int eown = wbase + lane;
    int4 edmy = edata[e0 + (eown < ecnt ? eown : ecnt - 1)];
    int jsw = ((l15 & 3) << 2) | (l15 >> 2);   // 4x4 transpose of l15

#pragma unroll
    for (int mt = 0; mt < 4; ++mt) {
        // A-row m = l15 holds edge swap(l15) of this tile
        int sA = mt * 16 + jsw;
        int rowv = __shfl(edmy.x, sA);
        int colv = __shfl(edmy.y, sA);
        const f16x8* rowp = (const f16x8*)(xh + (size_t)rowv * H);
        const f16x8* colp = (const f16x8*)(xh + (size_t)colv * H);
        f16x8 A[4];
        A[0] = rowp[quad];
        A[1] = rowp[4 + quad];
        A[2] = colp[quad];
        A[3] = colp[4 + quad];

        // ---- attention GEMM (bias in C-init) ----
        f32x4 ac0 = {ab1v0, ab1v0, ab1v0, ab1v0};
        f32x4 ac1 = {ab1v1, ab1v1, ab1v1, ab1v1};
#pragma unroll
        for (int kk = 0; kk < 4; ++kk) {
            ac0 = __builtin_amdgcn_mfma_f32_16x16x32_f16(A[kk], ab[0][kk], ac0, 0, 0, 0);
            ac1 = __builtin_amdgcn_mfma_f32_16x16x32_f16(A[kk], ab[1][kk], ac1, 0, 0, 0);
        }
        float p[4];
#pragma unroll
        for (int r = 0; r < 4; ++r)
            p[r] = fmaxf(ac0[r], 0.f) * aw20 + fmaxf(ac1[r], 0.f) * aw21;
#pragma unroll
        for (int off = 1; off < 16; off <<= 1) {
#pragma unroll
            for (int r = 0; r < 4; ++r) p[r] += __shfl_xor(p[r], off);
        }
        // C row quad*4+r == edge r*4+quad (relabel) -> slot mt*16+r*4+quad
        float fw[4];
#pragma unroll
        for (int r = 0; r < 4; ++r) {
            int sl = mt * 16 + r * 4 + quad;
            float ewv = (wbase + sl < ecnt)
                        ? __int_as_float(__shfl(edmy.z, sl)) : 0.f;
            fw[r] = ewv / (1.f + __expf(-(p[r] + ab2v)));
        }

        // ---- message GEMM (bias in C-init) ----
        f32x4 mc[4];
#pragma unroll
        for (int nt = 0; nt < 4; ++nt) {
            f32x4 cc = {bm[nt], bm[nt], bm[nt], bm[nt]};
#pragma unroll
            for (int kk = 0; kk < 4; ++kk)
                cc = __builtin_amdgcn_mfma_f32_16x16x32_f16(A[kk], mb[nt][kk], cc, 0, 0, 0);
            mc[nt] = cc;
        }

        // ---- epilogue: instruction r covers 4 CONTIGUOUS rows {4r..4r+3}
#pragma unroll
        for (int r = 0; r < 4; ++r) {
            int sl = wbase + mt * 16 + r * 4 + quad;
            if (sl < ecnt) {
                union { unsigned short u[4]; uint2 v; } pk;
#pragma unroll
                for (int nt = 0; nt < 4; ++nt) {
                    __hip_bfloat16 hb =
                        __float2bfloat16(fmaxf(mc[nt][r], 0.f) * fw[r]);
                    pk.u[nt] = *reinterpret_cast<unsigned short*>(&hb);
                }
                *(uint2*)(hfw + (size_t)sl * H + l15 * 4) = pk.v;
                if (l15 == 0) fwbuf[sl] = fw[r];
            }
        }
    }
}

// --------------------------------------------------------------- gather ----
__global__ __launch_bounds__(256) void gather_kernel(
    const __hip_bfloat16* __restrict__ hfw, const float* __restrict__ fwbuf,
    const int* __restrict__ startp, const int* __restrict__ deg,
    _Float16* __restrict__ agg, float* __restrict__ fwsum,
    int nlo, int nhi, int N, int E)
{
    int wid = (blockIdx.x * 256 + threadIdx.x) >> 6;
    int lane = threadIdx.x & 63;
    int n = nlo + wid;
    if (n >= nhi) return;
    int e0 = startp[nlo];
    int s = startp[n];
    int d = deg[n];
    int base = s - e0;
    float acc = 0.f;
    const __hip_bfloat16* hp = hfw + (size_t)base * H + lane;
    for (int i = 0; i < d; ++i) acc += __bfloat162float(hp[(size_t)i * H]);
    float fwl = 0.f;
    for (int i = lane; i < d; i += 64) fwl += fwbuf[base + i];
#pragma unroll
    for (int off = 32; off > 0; off >>= 1) fwl += __shfl_down(fwl, off);
    agg[(size_t)n * H + lane] = (_Float16)acc;
    if (lane == 0) fwsum[n] = fwl;
}

// --------------------------------------------------------------- update ----
__global__ __launch_bounds__(256, 2) void update_mfma_kernel(
    _Float16* __restrict__ xh, const _Float16* __restrict__ agg,
    const float* __restrict__ fwsum,
    const f16x8* __restrict__ Bfrag,  // [24][64] this layer
    const float* __restrict__ mbu,    // [64]
    const float* __restrict__ ub1, const float* __restrict__ ub2, int N)
{
    __shared__ __align__(16) _Float16 hlds[4][16 * 80];
    int wib = threadIdx.x >> 6;
    int lane = threadIdx.x & 63;
    int wid = (blockIdx.x * 256 + threadIdx.x) >> 6;
    int quad = lane >> 4, l15 = lane & 15;
    int nbase = wid * 64;
    if (nbase >= N) return;

    f16x8 Bu[8], Bm[8], Bw[8];
#pragma unroll
    for (int i = 0; i < 8; ++i) {
        Bu[i] = Bfrag[i * 64 + lane];
        Bm[i] = Bfrag[(8 + i) * 64 + lane];
        Bw[i] = Bfrag[(16 + i) * 64 + lane];
    }
    float mbuv[4], b1v[4], b2v[4];
#pragma unroll
    for (int nt = 0; nt < 4; ++nt) {
        mbuv[nt] = mbu[nt * 16 + l15];
        b1v[nt] = ub1[nt * 16 + l15];
        b2v[nt] = ub2[nt * 16 + l15];
    }

    for (int mt = 0; mt < 4; ++mt) {
        int na = nbase + mt * 16 + l15;
        if (na >= N) na = N - 1;
        const f16x8* xrow = (const f16x8*)(xh + (size_t)na * H);
        f16x8 Ax[2];
        Ax[0] = xrow[quad];
        Ax[1] = xrow[4 + quad];
        const f16x8* arow = (const f16x8*)(agg + (size_t)na * H);
        f16x8 Aa[2];
        Aa[0] = arow[quad];
        Aa[1] = arow[4 + quad];

        f32x4 Cx[4], Ca[4];
#pragma unroll
        for (int nt = 0; nt < 4; ++nt) {
            f32x4 cx = {0.f, 0.f, 0.f, 0.f}, ca = {0.f, 0.f, 0.f, 0.f};
#pragma unroll
            for (int kk = 0; kk < 2; ++kk) {
                cx = __builtin_amdgcn_mfma_f32_16x16x32_f16(Ax[kk], Bu[nt * 2 + kk], cx, 0, 0, 0);
                ca = __builtin_amdgcn_mfma_f32_16x16x32_f16(Aa[kk], Bm[nt * 2 + kk], ca, 0, 0, 0);
            }
            Cx[nt] = cx; Ca[nt] = ca;
        }

        int noder = nbase + mt * 16 + quad * 4;
        float fws_r[4], inv_r[4];
#pragma unroll
        for (int r = 0; r < 4; ++r) {
            int ng = noder + r; if (ng >= N) ng = N - 1;
            float fws = fwsum[ng];
            fws_r[r] = fws;
            inv_r[r] = 1.f / fmaxf(fws, 1e-6f);
        }

#pragma unroll
        for (int nt = 0; nt < 4; ++nt) {
#pragma unroll
            for (int r = 0; r < 4; ++r) {
                float hv = fmaxf(Cx[nt][r] + inv_r[r] * Ca[nt][r]
                                 + fws_r[r] * inv_r[r] * mbuv[nt] + b1v[nt], 0.f);
                hlds[wib][(quad * 4 + r) * 80 + nt * 16 + l15] = (_Float16)hv;
            }
        }
        __asm__ __volatile__("s_waitcnt lgkmcnt(0)" ::: "memory");
        f16x8 Ah[2];
        Ah[0] = *(const f16x8*)&hlds[wib][l15 * 80 + quad * 8];
        Ah[1] = *(const f16x8*)&hlds[wib][l15 * 80 + 32 + quad * 8];
        __asm__ __volatile__("s_waitcnt lgkmcnt(0)" ::: "memory");

        f32x4 C2[4];
#pragma unroll
        for (int nt = 0; nt < 4; ++nt) {
            f32x4 cc = {0.f, 0.f, 0.f, 0.f};
#pragma unroll
            for (int kk = 0; kk < 2; ++kk)
                cc = __builtin_amdgcn_mfma_f32_16x16x32_f16(Ah[kk], Bw[nt * 2 + kk], cc, 0, 0, 0);
            C2[nt] = cc;
        }

#pragma unroll
        for (int r = 0; r < 4; ++r) {
            int ng = noder + r;
            if (ng < N) {
#pragma unroll
                for (int nt = 0; nt < 4; ++nt) {
                    size_t idx = (size_t)ng * H + nt * 16 + l15;
                    float xo = (float)xh[idx];
                    xh[idx] = (_Float16)fmaxf(C2[nt][r] + b2v[nt] + xo, 0.f);
                }
            }
        }
    }
}

// ----------------------------------------------------------------- head ----
__global__ __launch_bounds__(256) void max_kernel(
    const _Float16* __restrict__ xh16, unsigned int* __restrict__ serp, int N)
{
    int j = threadIdx.x & (H - 1);
    int g = (blockIdx.x * 256 + threadIdx.x) >> 6;
    int stride = (gridDim.x * 256) >> 6;
    float m = 0.f;  // x >= 0 after relu
    for (int n = g; n < N; n += stride)
        m = fmaxf(m, (float)xh16[(size_t)n * H + j]);
    atomicMax(serp + j, __float_as_uint(m));
}

__global__ void head_kernel(const unsigned int* __restrict__ serp,
                            const float* __restrict__ hW,
                            const float* __restrict__ hb,
                            float* __restrict__ out)
{
    int j = threadIdx.x;  // 64 threads = 1 wave
    float v = __uint_as_float(serp[j]) * hW[j];
#pragma unroll
    for (int off = 32; off > 0; off >>= 1) v += __shfl_down(v, off);
    if (j == 0) out[0] = v + hb[0];
}

// --------------------------------------------------------------- launch ----
extern "C" void kernel_launch(void* const* d_in, const int* in_sizes, int n_in,
                              void* d_out, int out_size, void* d_ws, size_t ws_size,
                              hipStream_t stream)
{
    const float* nf  = (const float*)d_in[0];
    const int*   ei  = (const int*)d_in[1];
    const float* ew  = (const float*)d_in[2];
    const float* eW  = (const float*)d_in[3];
    const float* eb_ = (const float*)d_in[4];
    const float* mW1 = (const float*)d_in[5];
    const float* mb1 = (const float*)d_in[6];
    const float* mW2 = (const float*)d_in[7];
    const float* mb2 = (const float*)d_in[8];
    const float* aW1 = (const float*)d_in[9];
    const float* ab1 = (const float*)d_in[10];
    const float* aW2 = (const float*)d_in[11];
    const float* ab2 = (const float*)d_in[12];
    const float* uW1 = (const float*)d_in[13];
    const float* ub1 = (const float*)d_in[14];
    const float* uW2 = (const float*)d_in[15];
    const float* ub2 = (const float*)d_in[16];
    const float* hW  = (const float*)d_in[17];
    const float* hb  = (const float*)d_in[18];

    int N = in_sizes[0] / F;
    int E = in_sizes[2];
    const int* row = ei;
    const int* col = ei + E;

    size_t Nr = ((size_t)N + 3) & ~(size_t)3;
    size_t Er = ((size_t)E + 3) & ~(size_t)3;
    int NB = (E + 4095) / 4096;           // blocks in bucket passes
    int BS = (N + NBKT - 1) / NBKT;       // nodes per bucket
    size_t M = (size_t)NBKT * NB;         // bucket-count array size
    size_t Mr = (M + 3) & ~(size_t)3;

    // pick smallest chunk count k that fits ws
    int k = 8;
    size_t ce = 0;
    const int kcand[4] = {1, 2, 4, 8};
    for (int i = 0; i < 4; ++i) {
        int kk = kcand[i];
        size_t c = ((size_t)(E / kk) + 16384 + 3) & ~(size_t)3;
        size_t elems = Nr * 32 + Nr * 32 + Nr + 64 + 2 * Nr + 256
                     + 8192 + 4096 + 8192 + 128 + 12288
                     + 2 * Mr + 4 * Er + c + c * 32;
        if (elems * 4 <= ws_size || i == 3) { k = kk; ce = c; break; }
    }

    _Float16* xh  = (_Float16*)d_ws;                  // Nr*64 f16
    _Float16* agg = xh + Nr * 64;                     // Nr*64 f16
    float* fwsum  = (float*)(agg + Nr * 64);          // Nr
    unsigned int* serp = (unsigned int*)(fwsum + Nr); // 64
    int*   deg    = (int*)(serp + 64);                // Nr
    int*   startp = deg + Nr;                         // Nr
    int*   bsum   = startp + Nr;                      // 256
    f16x8* msgB   = (f16x8*)(bsum + 256);             // 2048 units
    f16x8* attB   = msgB + 2048;                      // 1024 units
    float* M2U    = (float*)(attB + 1024);            // 8192
    float* mbu    = M2U + 8192;                       // 128
    f16x8* updB   = (f16x8*)(mbu + 128);              // 3072 units
    int*   cnt    = (int*)(updB + 3072);              // Mr
    int*   off    = cnt + Mr;                         // Mr
    int4*  edata  = (int4*)(off + Mr);                // Er int4
    float* fwbuf  = (float*)(edata + Er);             // ce
    __hip_bfloat16* hfw = (__hip_bfloat16*)(fwbuf + ce);  // ce*H bf16

    int nb_n = (N + 255) / 256;
    int nb_e = (E + 255) / 256;
    int nb_scan = (N + 1023) / 1024;          // <=256 (N<=262144)
    int nb_scanM = (int)((M + 1023) / 1024);  // <=256

    hipMemsetAsync(deg, 0, (size_t)N * sizeof(int), stream);
    hist_kernel<<<nb_e, 256, 0, stream>>>(col, deg, E);
    scan1_kernel<<<nb_scan, 256, 0, stream>>>(deg, startp, bsum, N);
    scan2_kernel<<<1, 256, 0, stream>>>(bsum, nb_scan);
    scan3_kernel<<<nb_n, 256, 0, stream>>>(startp, bsum, N);

    count_bucket_kernel<<<NB, 256, 0, stream>>>(col, cnt, E, NB, BS);
    scan1_kernel<<<nb_scanM, 256, 0, stream>>>(cnt, off, bsum, (int)M);
    scan2_kernel<<<1, 256, 0, stream>>>(bsum, nb_scanM);
    scan3_kernel<<<(int)((M + 255) / 256), 256, 0, stream>>>(off, bsum, (int)M);
    place_kernel<<<NB, 256, 0, stream>>>(row, col, ew, off, edata, E, NB, BS);
    bucket_sort_kernel<<<NBKT, 256, 0, stream>>>(edata, off, NB, BS, E);

    packfrag_kernel<<<12, 256, 0, stream>>>(mW1, aW1, msgB, attB);
    prep_update_kernel<<<32, 256, 0, stream>>>(mW2, mb2, uW1, M2U, mbu);
    packfrag_upd_kernel<<<12, 256, 0, stream>>>(uW1, M2U, uW2, updB);
    embed_kernel<<<nb_n, 256, 0, stream>>>(nf, eW, eb_, xh, N);

    int npc = (N + k - 1) / k;
    int nb_edge = (int)((ce + 255) / 256);
    int nwaves_n = (N + 63) / 64;
    for (int l = 0; l < 2; ++l) {
        for (int c = 0; c < k; ++c) {
            int nlo = c * npc;
            if (nlo >= N) break;
            int nhi = (nlo + npc < N) ? nlo + npc : N;
            int nb_gath = (nhi - nlo + 3) / 4;
            edge_mfma_kernel<<<nb_edge, 256, 0, stream>>>(
                xh, edata, startp,
                msgB + (size_t)l * 16 * 64,
                attB + (size_t)l * 8 * 64,
                mb1 + (size_t)l * H,
                ab1 + (size_t)l * (H / 2),
                aW2 + (size_t)l * (H / 2), ab2 + (size_t)l,
                hfw, fwbuf, nlo, nhi, N, E);
            gather_kernel<<<nb_gath, 256, 0, stream>>>(
                hfw, fwbuf, startp, deg, agg, fwsum, nlo, nhi, N, E);
        }
        update_mfma_kernel<<<(nwaves_n + 3) / 4, 256, 0, stream>>>(
            xh, agg, fwsum,
            updB + (size_t)l * 24 * 64,
            mbu + (size_t)l * 64,
            ub1 + (size_t)l * H, ub2 + (size_t)l * H, N);
    }

    hipMemsetAsync(serp, 0, 64 * sizeof(unsigned int), stream);
    max_kernel<<<256, 256, 0, stream>>>(xh, serp, N);
    head_kernel<<<1, 64, 0, stream>>>(serp, hW, hb, (float*)d_out);
}

// Round 16
// 723.034 us; speedup vs baseline: 1.1393x; 1.0315x over previous
//
#include <hip/hip_runtime.h>
#include <hip/hip_bf16.h>
#include <math.h>

#define H 64
#define F 18
#define NBKT 512   // buckets for coarse partition (bucket ~ E/512 edges)

typedef _Float16 f16x8 __attribute__((ext_vector_type(8)));
typedef float f32x4 __attribute__((ext_vector_type(4)));

// ---------------------------------------------------------------- embed ----
__global__ __launch_bounds__(256) void embed_kernel(
    const float* __restrict__ nf, const float* __restrict__ W,
    const float* __restrict__ b, _Float16* __restrict__ xh, int N)
{
    int n = blockIdx.x * 256 + threadIdx.x;
    if (n >= N) return;
    float acc[H];
#pragma unroll
    for (int j = 0; j < H; ++j) acc[j] = b[j];
    const float* f = nf + (long)n * F;
#pragma unroll
    for (int i = 0; i < F; ++i) {
        float c = f[i];
        const float* w = W + i * H;
#pragma unroll
        for (int j = 0; j < H; ++j) acc[j] += c * w[j];
    }
    union { uint4 v[8]; _Float16 h[64]; } O;
#pragma unroll
    for (int j = 0; j < H; ++j) O.h[j] = (_Float16)fmaxf(acc[j], 0.f);
    uint4* xo = (uint4*)(xh + (size_t)n * H);
#pragma unroll
    for (int i = 0; i < 8; ++i) xo[i] = O.v[i];
}

// ------------------------------------------------- B-fragment prepack -----
__global__ __launch_bounds__(256) void packfrag_kernel(
    const float* __restrict__ mW1, const float* __restrict__ aW1,
    f16x8* __restrict__ msgB, f16x8* __restrict__ attB)
{
    int t = blockIdx.x * 256 + threadIdx.x;  // 0..3071
    if (t >= 3072) return;
    int lane = t & 63;
    int frag = t >> 6;            // 0..47
    int l = frag / 24, f = frag % 24;
    int quad = lane >> 4, l15 = lane & 15;
    f16x8 v;
    if (f < 16) {
        int nt = f >> 2, kk = f & 3;
        const float* W = mW1 + (size_t)l * 128 * 64;
#pragma unroll
        for (int j = 0; j < 8; ++j) {
            int k = kk * 32 + quad * 8 + j;
            v[j] = (_Float16)W[k * 64 + nt * 16 + l15];
        }
        msgB[((size_t)l * 16 + f) * 64 + lane] = v;
    } else {
        int f2 = f - 16;
        int nt = f2 >> 2, kk = f2 & 3;
        const float* W = aW1 + (size_t)l * 128 * 32;
#pragma unroll
        for (int j = 0; j < 8; ++j) {
            int k = kk * 32 + quad * 8 + j;
            v[j] = (_Float16)W[k * 32 + nt * 16 + l15];
        }
        attB[((size_t)l * 8 + f2) * 64 + lane] = v;
    }
}

// ---------------------------------------------- update-path precompute ----
__global__ __launch_bounds__(256) void prep_update_kernel(
    const float* __restrict__ mW2, const float* __restrict__ mb2,
    const float* __restrict__ uW1,
    float* __restrict__ M2U, float* __restrict__ mbu)
{
    int t = blockIdx.x * 256 + threadIdx.x;  // 0..8191
    if (t >= 2 * 64 * 64) return;
    int l = t >> 12, r = t & 4095;
    int i = r >> 6, j = r & 63;
    const float* W2 = mW2 + (size_t)l * 4096;
    const float* U1b = uW1 + (size_t)l * 8192 + 4096;  // rows 64..127
    float s = 0.f;
    for (int k = 0; k < 64; ++k) s += W2[i * 64 + k] * U1b[k * 64 + j];
    M2U[t] = s;
    if (i == 0) {
        float sb = 0.f;
        const float* b2 = mb2 + (size_t)l * 64;
        for (int k = 0; k < 64; ++k) sb += b2[k] * U1b[k * 64 + j];
        mbu[l * 64 + j] = sb;
    }
}

// g==1 (M2U) fragment rows PERMUTED: agg stored at pos=l15*4+nt (true col
// c = nt*16+l15), so k-th A element multiplies M2U row ((k&3)<<4)|(k>>2).
__global__ __launch_bounds__(256) void packfrag_upd_kernel(
    const float* __restrict__ uW1, const float* __restrict__ M2U,
    const float* __restrict__ uW2, f16x8* __restrict__ updB)
{
    int t = blockIdx.x * 256 + threadIdx.x;  // 0..3071
    if (t >= 3072) return;
    int lane = t & 63;
    int frag = t >> 6;  // 0..47
    int l = frag / 24, f = frag % 24;
    int quad = lane >> 4, l15 = lane & 15;
    int g = f >> 3, ff = f & 7;
    int nt = ff >> 1, kk = ff & 1;
    const float* src;
    if (g == 0)      src = uW1 + (size_t)l * 8192;       // rows 0..63
    else if (g == 1) src = M2U + (size_t)l * 4096;
    else             src = uW2 + (size_t)l * 4096;
    f16x8 v;
#pragma unroll
    for (int j = 0; j < 8; ++j) {
        int k = kk * 32 + quad * 8 + j;
        int ks = (g == 1) ? (((k & 3) << 4) | (k >> 2)) : k;
        v[j] = (_Float16)src[ks * 64 + nt * 16 + l15];
    }
    updB[(size_t)frag * 64 + lane] = v;
}

// ----------------------------------------------- counting sort metadata ---
__global__ __launch_bounds__(256) void hist_kernel(
    const int* __restrict__ col, int* __restrict__ deg, int E)
{
    int e = blockIdx.x * 256 + threadIdx.x;
    if (e < E) atomicAdd(deg + col[e], 1);
}

__global__ __launch_bounds__(256) void scan1_kernel(
    const int* __restrict__ deg, int* __restrict__ part,
    int* __restrict__ bsum, int N)
{
    __shared__ int lds[256];
    int t = threadIdx.x;
    int base = blockIdx.x * 1024 + t * 4;
    int v[4];
#pragma unroll
    for (int s = 0; s < 4; ++s) v[s] = (base + s < N) ? deg[base + s] : 0;
    int sum = v[0] + v[1] + v[2] + v[3];
    lds[t] = sum;
    __syncthreads();
    for (int off = 1; off < 256; off <<= 1) {
        int xv = (t >= off) ? lds[t - off] : 0;
        __syncthreads();
        lds[t] += xv;
        __syncthreads();
    }
    int excl = lds[t] - sum;
    if (t == 255) bsum[blockIdx.x] = lds[255];
    int p = excl;
#pragma unroll
    for (int s = 0; s < 4; ++s) {
        if (base + s < N) part[base + s] = p;
        p += v[s];
    }
}

__global__ __launch_bounds__(256) void scan2_kernel(int* __restrict__ bsum, int nb)
{
    __shared__ int lds[256];
    int t = threadIdx.x;
    int v = (t < nb) ? bsum[t] : 0;
    lds[t] = v;
    __syncthreads();
    for (int off = 1; off < 256; off <<= 1) {
        int xv = (t >= off) ? lds[t - off] : 0;
        __syncthreads();
        lds[t] += xv;
        __syncthreads();
    }
    if (t < nb) bsum[t] = lds[t] - v;
}

__global__ __launch_bounds__(256) void scan3_kernel(
    int* __restrict__ part, const int* __restrict__ bsum, int N)
{
    int i = blockIdx.x * 256 + threadIdx.x;
    if (i >= N) return;
    part[i] = part[i] + bsum[i >> 10];
}

// ----------------------------------------- coarse bucket partition --------
__global__ __launch_bounds__(256) void count_bucket_kernel(
    const int* __restrict__ col, int* __restrict__ cnt,
    int E, int NB, int BS)
{
    __shared__ int lc[NBKT];
    int t = threadIdx.x;
    for (int i = t; i < NBKT; i += 256) lc[i] = 0;
    __syncthreads();
#pragma unroll
    for (int s = 0; s < 16; ++s) {
        int e = blockIdx.x * 4096 + s * 256 + t;
        if (e < E) atomicAdd(lc + (unsigned)col[e] / (unsigned)BS, 1);
    }
    __syncthreads();
    for (int i = t; i < NBKT; i += 256)
        cnt[(size_t)i * NB + blockIdx.x] = lc[i];
}

__global__ __launch_bounds__(256) void place_kernel(
    const int* __restrict__ row, const int* __restrict__ col,
    const float* __restrict__ ew, const int* __restrict__ off,
    int4* __restrict__ edata, int E, int NB, int BS)
{
    __shared__ int lc[NBKT];
    int t = threadIdx.x;
    for (int i = t; i < NBKT; i += 256) lc[i] = 0;
    __syncthreads();
#pragma unroll
    for (int s = 0; s < 16; ++s) {
        int e = blockIdx.x * 4096 + s * 256 + t;
        if (e < E) {
            int cv = col[e];
            int c = (unsigned)cv / (unsigned)BS;
            int r = atomicAdd(lc + c, 1);
            int pos = off[(size_t)c * NB + blockIdx.x] + r;
            edata[pos] = make_int4(row[e], cv, __float_as_int(ew[e]), 0);
        }
    }
}

// ------------------------------------------- per-bucket in-place sort -----
__global__ __launch_bounds__(256) void bucket_sort_kernel(
    int4* __restrict__ edata, const int* __restrict__ off,
    int NB, int BS, int E)
{
    __shared__ int hist[512];
    __shared__ int psum[256];
    int b = blockIdx.x;
    int t = threadIdx.x;
    int base = off[(size_t)b * NB];
    int end  = (b + 1 < NBKT) ? off[(size_t)(b + 1) * NB] : E;
    int cnt = end - base;
    int nlo = b * BS;
    hist[t] = 0; hist[256 + t] = 0;
    __syncthreads();

    int4 regs[16];
#pragma unroll
    for (int ii = 0; ii < 16; ++ii) {
        int i = t + ii * 256;
        if (i < cnt) {
            regs[ii] = edata[base + i];
            atomicAdd(hist + (regs[ii].y - nlo), 1);
        }
    }
    __syncthreads();

    int a0 = hist[2 * t], a1 = hist[2 * t + 1];
    int s = a0 + a1;
    psum[t] = s;
    __syncthreads();
    for (int o = 1; o < 256; o <<= 1) {
        int xv = (t >= o) ? psum[t - o] : 0;
        __syncthreads();
        psum[t] += xv;
        __syncthreads();
    }
    int excl = psum[t] - s;
    hist[2 * t] = excl;
    hist[2 * t + 1] = excl + a0;
    __syncthreads();

#pragma unroll
    for (int ii = 0; ii < 16; ++ii) {
        int i = t + ii * 256;
        if (i < cnt) {
            int pos = atomicAdd(hist + (regs[ii].y - nlo), 1);
            edata[base + pos] = regs[ii];
        }
    }
}

// ----------------------------------------------------------------- edge ----
// R16: software-pipelined A-loads (double buffer). Tile mt+1's 4 dwordx4
// loads issue before tile mt's MFMA/epilogue, hiding HBM latency behind
// ~400cyc of compute. Addresses come from shuffles of the preloaded edata
// (VALU-only, no load chain). Everything else as R15.
__global__ __launch_bounds__(256) void edge_mfma_kernel(
    const _Float16* __restrict__ xh,
    const int4* __restrict__ edata, const int* __restrict__ startp,
    const f16x8* __restrict__ msgB,  // [16][64] this layer
    const f16x8* __restrict__ attB,  // [8][64]
    const float* __restrict__ b1, const float* __restrict__ ab1,
    const float* __restrict__ aW2, const float* __restrict__ ab2,
    __hip_bfloat16* __restrict__ hfw, float* __restrict__ fwbuf,
    int nlo, int nhi, int N, int E)
{
    int e0 = startp[nlo];
    int e1 = (nhi < N) ? startp[nhi] : E;
    int ecnt = e1 - e0;
    int wid = (blockIdx.x * 256 + threadIdx.x) >> 6;
    int lane = threadIdx.x & 63;
    int wbase = wid * 64;
    if (wbase >= ecnt) return;
    int quad = lane >> 4, l15 = lane & 15;

    f16x8 mb[4][4], ab[2][4];
#pragma unroll
    for (int nt = 0; nt < 4; ++nt)
#pragma unroll
        for (int kk = 0; kk < 4; ++kk)
            mb[nt][kk] = msgB[(nt * 4 + kk) * 64 + lane];
#pragma unroll
    for (int nt = 0; nt < 2; ++nt)
#pragma unroll
        for (int kk = 0; kk < 4; ++kk)
            ab[nt][kk] = attB[(nt * 4 + kk) * 64 + lane];

    float ab1v0 = ab1[l15], ab1v1 = ab1[16 + l15];
    float aw20 = aW2[l15], aw21 = aW2[16 + l15];
    float ab2v = ab2[0];
    float bm[4];
#pragma unroll
    for (int nt = 0; nt < 4; ++nt) bm[nt] = b1[nt * 16 + l15];

    // one edata load per lane (own edge); everything else via shuffles
    int eown = wbase + lane;
    int4 edmy = edata[e0 + (eown < ecnt ? eown : ecnt - 1)];
    int jsw = ((l15 & 3) << 2) | (l15 >> 2);   // 4x4 transpose of l15

    // ---- prologue: load A for tile 0 ----
    f16x8 Acur[4], Anxt[4];
    {
        int sA = jsw;
        int rowv = __shfl(edmy.x, sA);
        int colv = __shfl(edmy.y, sA);
        const f16x8* rowp = (const f16x8*)(xh + (size_t)rowv * H);
        const f16x8* colp = (const f16x8*)(xh + (size_t)colv * H);
        Acur[0] = rowp[quad];
        Acur[1] = rowp[4 + quad];
        Acur[2] = colp[quad];
        Acur[3] = colp[4 + quad];
    }

#pragma unroll
    for (int mt = 0; mt < 4; ++mt) {
        // ---- issue next tile's loads first (overlap with compute) ----
        if (mt < 3) {
            int sA = (mt + 1) * 16 + jsw;
            int rowv = __shfl(edmy.x, sA);
            int colv = __shfl(edmy.y, sA);
            const f16x8* rowp = (const f16x8*)(xh + (size_t)rowv * H);
            const f16x8* colp = (const f16x8*)(xh + (size_t)colv * H);
            Anxt[0] = rowp[quad];
            Anxt[1] = rowp[4 + quad];
            Anxt[2] = colp[quad];
            Anxt[3] = colp[4 + quad];
        }

        // ---- attention GEMM (bias in C-init) ----
        f32x4 ac0 = {ab1v0, ab1v0, ab1v0, ab1v0};
        f32x4 ac1 = {ab1v1, ab1v1, ab1v1, ab1v1};
#pragma unroll
        for (int kk = 0; kk < 4; ++kk) {
            ac0 = __builtin_amdgcn_mfma_f32_16x16x32_f16(Acur[kk], ab[0][kk], ac0, 0, 0, 0);
            ac1 = __builtin_amdgcn_mfma_f32_16x16x32_f16(Acur[kk], ab[1][kk], ac1, 0, 0, 0);
        }
        float p[4];
#pragma unroll
        for (int r = 0; r < 4; ++r)
            p[r] = fmaxf(ac0[r], 0.f) * aw20 + fmaxf(ac1[r], 0.f) * aw21;
#pragma unroll
        for (int off = 1; off < 16; off <<= 1) {
#pragma unroll
            for (int r = 0; r < 4; ++r) p[r] += __shfl_xor(p[r], off);
        }
        // C row quad*4+r == edge r*4+quad (relabel) -> slot mt*16+r*4+quad
        float fw[4];
#pragma unroll
        for (int r = 0; r < 4; ++r) {
            int sl = mt * 16 + r * 4 + quad;
            float ewv = (wbase + sl < ecnt)
                        ? __int_as_float(__shfl(edmy.z, sl)) : 0.f;
            fw[r] = ewv / (1.f + __expf(-(p[r] + ab2v)));
        }

        // ---- message GEMM (bias in C-init) ----
        f32x4 mc[4];
#pragma unroll
        for (int nt = 0; nt < 4; ++nt) {
            f32x4 cc = {bm[nt], bm[nt], bm[nt], bm[nt]};
#pragma unroll
            for (int kk = 0; kk < 4; ++kk)
                cc = __builtin_amdgcn_mfma_f32_16x16x32_f16(Acur[kk], mb[nt][kk], cc, 0, 0, 0);
            mc[nt] = cc;
        }

        // ---- epilogue: instruction r covers 4 CONTIGUOUS rows {4r..4r+3}
#pragma unroll
        for (int r = 0; r < 4; ++r) {
            int sl = wbase + mt * 16 + r * 4 + quad;
            if (sl < ecnt) {
                union { unsigned short u[4]; uint2 v; } pk;
#pragma unroll
                for (int nt = 0; nt < 4; ++nt) {
                    __hip_bfloat16 hb =
                        __float2bfloat16(fmaxf(mc[nt][r], 0.f) * fw[r]);
                    pk.u[nt] = *reinterpret_cast<unsigned short*>(&hb);
                }
                *(uint2*)(hfw + (size_t)sl * H + l15 * 4) = pk.v;
                if (l15 == 0) fwbuf[sl] = fw[r];
            }
        }

        // ---- rotate buffers ----
        if (mt < 3) {
#pragma unroll
            for (int i = 0; i < 4; ++i) Acur[i] = Anxt[i];
        }
    }
}

// --------------------------------------------------------------- gather ----
__global__ __launch_bounds__(256) void gather_kernel(
    const __hip_bfloat16* __restrict__ hfw, const float* __restrict__ fwbuf,
    const int* __restrict__ startp, const int* __restrict__ deg,
    _Float16* __restrict__ agg, float* __restrict__ fwsum,
    int nlo, int nhi, int N, int E)
{
    int wid = (blockIdx.x * 256 + threadIdx.x) >> 6;
    int lane = threadIdx.x & 63;
    int n = nlo + wid;
    if (n >= nhi) return;
    int e0 = startp[nlo];
    int s = startp[n];
    int d = deg[n];
    int base = s - e0;
    float acc = 0.f;
    const __hip_bfloat16* hp = hfw + (size_t)base * H + lane;
    for (int i = 0; i < d; ++i) acc += __bfloat162float(hp[(size_t)i * H]);
    float fwl = 0.f;
    for (int i = lane; i < d; i += 64) fwl += fwbuf[base + i];
#pragma unroll
    for (int off = 32; off > 0; off >>= 1) fwl += __shfl_down(fwl, off);
    agg[(size_t)n * H + lane] = (_Float16)acc;
    if (lane == 0) fwsum[n] = fwl;
}

// --------------------------------------------------------------- update ----
__global__ __launch_bounds__(256, 2) void update_mfma_kernel(
    _Float16* __restrict__ xh, const _Float16* __restrict__ agg,
    const float* __restrict__ fwsum,
    const f16x8* __restrict__ Bfrag,  // [24][64] this layer
    const float* __restrict__ mbu,    // [64]
    const float* __restrict__ ub1, const float* __restrict__ ub2, int N)
{
    __shared__ __align__(16) _Float16 hlds[4][16 * 80];
    int wib = threadIdx.x >> 6;
    int lane = threadIdx.x & 63;
    int wid = (blockIdx.x * 256 + threadIdx.x) >> 6;
    int quad = lane >> 4, l15 = lane & 15;
    int nbase = wid * 64;
    if (nbase >= N) return;

    f16x8 Bu[8], Bm[8], Bw[8];
#pragma unroll
    for (int i = 0; i < 8; ++i) {
        Bu[i] = Bfrag[i * 64 + lane];
        Bm[i] = Bfrag[(8 + i) * 64 + lane];
        Bw[i] = Bfrag[(16 + i) * 64 + lane];
    }
    float mbuv[4], b1v[4], b2v[4];
#pragma unroll
    for (int nt = 0; nt < 4; ++nt) {
        mbuv[nt] = mbu[nt * 16 + l15];
        b1v[nt] = ub1[nt * 16 + l15];
        b2v[nt] = ub2[nt * 16 + l15];
    }

    for (int mt = 0; mt < 4; ++mt) {
        int na = nbase + mt * 16 + l15;
        if (na >= N) na = N - 1;
        const f16x8* xrow = (const f16x8*)(xh + (size_t)na * H);
        f16x8 Ax[2];
        Ax[0] = xrow[quad];
        Ax[1] = xrow[4 + quad];
        const f16x8* arow = (const f16x8*)(agg + (size_t)na * H);
        f16x8 Aa[2];
        Aa[0] = arow[quad];
        Aa[1] = arow[4 + quad];

        f32x4 Cx[4], Ca[4];
#pragma unroll
        for (int nt = 0; nt < 4; ++nt) {
            f32x4 cx = {0.f, 0.f, 0.f, 0.f}, ca = {0.f, 0.f, 0.f, 0.f};
#pragma unroll
            for (int kk = 0; kk < 2; ++kk) {
                cx = __builtin_amdgcn_mfma_f32_16x16x32_f16(Ax[kk], Bu[nt * 2 + kk], cx, 0, 0, 0);
                ca = __builtin_amdgcn_mfma_f32_16x16x32_f16(Aa[kk], Bm[nt * 2 + kk], ca, 0, 0, 0);
            }
            Cx[nt] = cx; Ca[nt] = ca;
        }

        int noder = nbase + mt * 16 + quad * 4;
        float fws_r[4], inv_r[4];
#pragma unroll
        for (int r = 0; r < 4; ++r) {
            int ng = noder + r; if (ng >= N) ng = N - 1;
            float fws = fwsum[ng];
            fws_r[r] = fws;
            inv_r[r] = 1.f / fmaxf(fws, 1e-6f);
        }

#pragma unroll
        for (int nt = 0; nt < 4; ++nt) {
#pragma unroll
            for (int r = 0; r < 4; ++r) {
                float hv = fmaxf(Cx[nt][r] + inv_r[r] * Ca[nt][r]
                                 + fws_r[r] * inv_r[r] * mbuv[nt] + b1v[nt], 0.f);
                hlds[wib][(quad * 4 + r) * 80 + nt * 16 + l15] = (_Float16)hv;
            }
        }
        __asm__ __volatile__("s_waitcnt lgkmcnt(0)" ::: "memory");
        f16x8 Ah[2];
        Ah[0] = *(const f16x8*)&hlds[wib][l15 * 80 + quad * 8];
        Ah[1] = *(const f16x8*)&hlds[wib][l15 * 80 + 32 + quad * 8];
        __asm__ __volatile__("s_waitcnt lgkmcnt(0)" ::: "memory");

        f32x4 C2[4];
#pragma unroll
        for (int nt = 0; nt < 4; ++nt) {
            f32x4 cc = {0.f, 0.f, 0.f, 0.f};
#pragma unroll
            for (int kk = 0; kk < 2; ++kk)
                cc = __builtin_amdgcn_mfma_f32_16x16x32_f16(Ah[kk], Bw[nt * 2 + kk], cc, 0, 0, 0);
            C2[nt] = cc;
        }

#pragma unroll
        for (int r = 0; r < 4; ++r) {
            int ng = noder + r;
            if (ng < N) {
#pragma unroll
                for (int nt = 0; nt < 4; ++nt) {
                    size_t idx = (size_t)ng * H + nt * 16 + l15;
                    float xo = (float)xh[idx];
                    xh[idx] = (_Float16)fmaxf(C2[nt][r] + b2v[nt] + xo, 0.f);
                }
            }
        }
    }
}

// ----------------------------------------------------------------- head ----
__global__ __launch_bounds__(256) void max_kernel(
    const _Float16* __restrict__ xh16, unsigned int* __restrict__ serp, int N)
{
    int j = threadIdx.x & (H - 1);
    int g = (blockIdx.x * 256 + threadIdx.x) >> 6;
    int stride = (gridDim.x * 256) >> 6;
    float m = 0.f;  // x >= 0 after relu
    for (int n = g; n < N; n += stride)
        m = fmaxf(m, (float)xh16[(size_t)n * H + j]);
    atomicMax(serp + j, __float_as_uint(m));
}

__global__ void head_kernel(const unsigned int* __restrict__ serp,
                            const float* __restrict__ hW,
                            const float* __restrict__ hb,
                            float* __restrict__ out)
{
    int j = threadIdx.x;  // 64 threads = 1 wave
    float v = __uint_as_float(serp[j]) * hW[j];
#pragma unroll
    for (int off = 32; off > 0; off >>= 1) v += __shfl_down(v, off);
    if (j == 0) out[0] = v + hb[0];
}

// --------------------------------------------------------------- launch ----
extern "C" void kernel_launch(void* const* d_in, const int* in_sizes, int n_in,
                              void* d_out, int out_size, void* d_ws, size_t ws_size,
                              hipStream_t stream)
{
    const float* nf  = (const float*)d_in[0];
    const int*   ei  = (const int*)d_in[1];
    const float* ew  = (const float*)d_in[2];
    const float* eW  = (const float*)d_in[3];
    const float* eb_ = (const float*)d_in[4];
    const float* mW1 = (const float*)d_in[5];
    const float* mb1 = (const float*)d_in[6];
    const float* mW2 = (const float*)d_in[7];
    const float* mb2 = (const float*)d_in[8];
    const float* aW1 = (const float*)d_in[9];
    const float* ab1 = (const float*)d_in[10];
    const float* aW2 = (const float*)d_in[11];
    const float* ab2 = (const float*)d_in[12];
    const float* uW1 = (const float*)d_in[13];
    const float* ub1 = (const float*)d_in[14];
    const float* uW2 = (const float*)d_in[15];
    const float* ub2 = (const float*)d_in[16];
    const float* hW  = (const float*)d_in[17];
    const float* hb  = (const float*)d_in[18];

    int N = in_sizes[0] / F;
    int E = in_sizes[2];
    const int* row = ei;
    const int* col = ei + E;

    size_t Nr = ((size_t)N + 3) & ~(size_t)3;
    size_t Er = ((size_t)E + 3) & ~(size_t)3;
    int NB = (E + 4095) / 4096;           // blocks in bucket passes
    int BS = (N + NBKT - 1) / NBKT;       // nodes per bucket
    size_t M = (size_t)NBKT * NB;         // bucket-count array size
    size_t Mr = (M + 3) & ~(size_t)3;

    // pick smallest chunk count k that fits ws
    int k = 8;
    size_t ce = 0;
    const int kcand[4] = {1, 2, 4, 8};
    for (int i = 0; i < 4; ++i) {
        int kk = kcand[i];
        size_t c = ((size_t)(E / kk) + 16384 + 3) & ~(size_t)3;
        size_t elems = Nr * 32 + Nr * 32 + Nr + 64 + 2 * Nr + 256
                     + 8192 + 4096 + 8192 + 128 + 12288
                     + 2 * Mr + 4 * Er + c + c * 32;
        if (elems * 4 <= ws_size || i == 3) { k = kk; ce = c; break; }
    }

    _Float16* xh  = (_Float16*)d_ws;                  // Nr*64 f16
    _Float16* agg = xh + Nr * 64;                     // Nr*64 f16
    float* fwsum  = (float*)(agg + Nr * 64);          // Nr
    unsigned int* serp = (unsigned int*)(fwsum + Nr); // 64
    int*   deg    = (int*)(serp + 64);                // Nr
    int*   startp = deg + Nr;                         // Nr
    int*   bsum   = startp + Nr;                      // 256
    f16x8* msgB   = (f16x8*)(bsum + 256);             // 2048 units
    f16x8* attB   = msgB + 2048;                      // 1024 units
    float* M2U    = (float*)(attB + 1024);            // 8192
    float* mbu    = M2U + 8192;                       // 128
    f16x8* updB   = (f16x8*)(mbu + 128);              // 3072 units
    int*   cnt    = (int*)(updB + 3072);              // Mr
    int*   off    = cnt + Mr;                         // Mr
    int4*  edata  = (int4*)(off + Mr);                // Er int4
    float* fwbuf  = (float*)(edata + Er);             // ce
    __hip_bfloat16* hfw = (__hip_bfloat16*)(fwbuf + ce);  // ce*H bf16

    int nb_n = (N + 255) / 256;
    int nb_e = (E + 255) / 256;
    int nb_scan = (N + 1023) / 1024;          // <=256 (N<=262144)
    int nb_scanM = (int)((M + 1023) / 1024);  // <=256

    hipMemsetAsync(deg, 0, (size_t)N * sizeof(int), stream);
    hist_kernel<<<nb_e, 256, 0, stream>>>(col, deg, E);
    scan1_kernel<<<nb_scan, 256, 0, stream>>>(deg, startp, bsum, N);
    scan2_kernel<<<1, 256, 0, stream>>>(bsum, nb_scan);
    scan3_kernel<<<nb_n, 256, 0, stream>>>(startp, bsum, N);

    count_bucket_kernel<<<NB, 256, 0, stream>>>(col, cnt, E, NB, BS);
    scan1_kernel<<<nb_scanM, 256, 0, stream>>>(cnt, off, bsum, (int)M);
    scan2_kernel<<<1, 256, 0, stream>>>(bsum, nb_scanM);
    scan3_kernel<<<(int)((M + 255) / 256), 256, 0, stream>>>(off, bsum, (int)M);
    place_kernel<<<NB, 256, 0, stream>>>(row, col, ew, off, edata, E, NB, BS);
    bucket_sort_kernel<<<NBKT, 256, 0, stream>>>(edata, off, NB, BS, E);

    packfrag_kernel<<<12, 256, 0, stream>>>(mW1, aW1, msgB, attB);
    prep_update_kernel<<<32, 256, 0, stream>>>(mW2, mb2, uW1, M2U, mbu);
    packfrag_upd_kernel<<<12, 256, 0, stream>>>(uW1, M2U, uW2, updB);
    embed_kernel<<<nb_n, 256, 0, stream>>>(nf, eW, eb_, xh, N);

    int npc = (N + k - 1) / k;
    int nb_edge = (int)((ce + 255) / 256);
    int nwaves_n = (N + 63) / 64;
    for (int l = 0; l < 2; ++l) {
        for (int c = 0; c < k; ++c) {
            int nlo = c * npc;
            if (nlo >= N) break;
            int nhi = (nlo + npc < N) ? nlo + npc : N;
            int nb_gath = (nhi - nlo + 3) / 4;
            edge_mfma_kernel<<<nb_edge, 256, 0, stream>>>(
                xh, edata, startp,
                msgB + (size_t)l * 16 * 64,
                attB + (size_t)l * 8 * 64,
                mb1 + (size_t)l * H,
                ab1 + (size_t)l * (H / 2),
                aW2 + (size_t)l * (H / 2), ab2 + (size_t)l,
                hfw, fwbuf, nlo, nhi, N, E);
            gather_kernel<<<nb_gath, 256, 0, stream>>>(
                hfw, fwbuf, startp, deg, agg, fwsum, nlo, nhi, N, E);
        }
        update_mfma_kernel<<<(nwaves_n + 3) / 4, 256, 0, stream>>>(
            xh, agg, fwsum,
            updB + (size_t)l * 24 * 64,
            mbu + (size_t)l * 64,
            ub1 + (size_t)l * H, ub2 + (size_t)l * H, N);
    }

    hipMemsetAsync(serp, 0, 64 * sizeof(unsigned int), stream);
    max_kernel<<<256, 256, 0, stream>>>(xh, serp, N);
    head_kernel<<<1, 64, 0, stream>>>(serp, hW, hb, (float*)d_out);
}